// Round 1
// baseline (560.847 us; speedup 1.0000x reference)
//
#include <hip/hip_runtime.h>

#define Bc 4
#define Hc 16
#define Lc 4096
#define Dc 1024
#define Mc (Bc*Lc)
#define EPSc 1e-6f

typedef __bf16 bf16x8 __attribute__((ext_vector_type(8)));
typedef __bf16 bf16x4 __attribute__((ext_vector_type(4)));
typedef float f32x4 __attribute__((ext_vector_type(4)));

typedef __attribute__((address_space(3))) void lds_vt;
typedef const __attribute__((address_space(1))) void gbl_vt;

__device__ __forceinline__ void gll16(const void* g, void* l) {
  __builtin_amdgcn_global_load_lds((gbl_vt*)g, (lds_vt*)l, 16, 0, 0);
}

// ---------------- converts ----------------
__global__ __launch_bounds__(256) void conv_bf16(const float* __restrict__ X, __bf16* __restrict__ Y) {
  const int i = blockIdx.x * 256 + threadIdx.x;
  const float4 v = ((const float4*)X)[i];
  bf16x4 o;
  o[0] = (__bf16)v.x; o[1] = (__bf16)v.y; o[2] = (__bf16)v.z; o[3] = (__bf16)v.w;
  ((bf16x4*)Y)[i] = o;
}

__global__ __launch_bounds__(256) void wt_conv(const float* __restrict__ W, __bf16* __restrict__ Wt) {
  __shared__ float t[32][33];
  const int n0 = blockIdx.x << 5, k0 = blockIdx.y << 5;
  const int tx = threadIdx.x, ty = threadIdx.y;  // block (32,8)
#pragma unroll
  for (int i = 0; i < 4; ++i)
    t[ty + 8 * i][tx] = W[(size_t)(k0 + ty + 8 * i) * Dc + n0 + tx];
  __syncthreads();
#pragma unroll
  for (int i = 0; i < 4; ++i)
    Wt[(size_t)(n0 + ty + 8 * i) * Dc + k0 + tx] = (__bf16)t[tx][ty + 8 * i];
}

// ---------------- GEMM: C[M,N] = act(A[M,K] @ Bt[N,K]^T + bias) ----------------
template <int ACT, int OUTBF>
__global__ __launch_bounds__(256) void gemm_bt(
    const __bf16* __restrict__ A, const __bf16* __restrict__ Bt,
    const float* __restrict__ bias, void* __restrict__ Cp,
    int M, int N, int K) {
  __shared__ __bf16 Al[128 * 32];
  __shared__ __bf16 Bl[128 * 32];
  const int tid = threadIdx.x;
  const int wid = tid >> 6;
  const int lane = tid & 63;
  const int row0 = blockIdx.x << 7;
  const int col0 = blockIdx.y << 7;

  const int rA = tid >> 2;          // staging row (chunk = tid)
  const int ca = (tid & 3) << 3;    // staging col offset (elems)
  const __bf16* gA0 = A + (size_t)(row0 + rA) * K + ca;
  const __bf16* gB0 = Bt + (size_t)(col0 + rA) * K + ca;
  const size_t k64 = (size_t)64 * K;
  __bf16* lA0 = Al + (wid << 9);
  __bf16* lB0 = Bl + (wid << 9);

  const int wr = wid >> 1, wc = wid & 1;
  const int lr = lane & 15, lk = (lane >> 4) << 3;
  const __bf16* Ard = Al + ((wr << 6) + lr) * 32 + lk;
  const __bf16* Brd = Bl + ((wc << 6) + lr) * 32 + lk;

  f32x4 acc[4][4] = {};

  for (int kk = 0; kk < K; kk += 32) {
    gll16(gA0 + kk, lA0);
    gll16(gA0 + k64 + kk, lA0 + 2048);
    gll16(gB0 + kk, lB0);
    gll16(gB0 + k64 + kk, lB0 + 2048);
    __syncthreads();
    bf16x8 af[4], bfr[4];
#pragma unroll
    for (int i = 0; i < 4; ++i) {
      af[i]  = *(const bf16x8*)(Ard + i * 512);
      bfr[i] = *(const bf16x8*)(Brd + i * 512);
    }
#pragma unroll
    for (int mi = 0; mi < 4; ++mi)
#pragma unroll
      for (int ni = 0; ni < 4; ++ni)
        acc[mi][ni] = __builtin_amdgcn_mfma_f32_16x16x32_bf16(af[mi], bfr[ni], acc[mi][ni], 0, 0, 0);
    __syncthreads();
  }

  const int orow = row0 + (wr << 6) + ((lane >> 4) << 2);
  const int ocol = col0 + (wc << 6) + lr;
#pragma unroll
  for (int ni = 0; ni < 4; ++ni) {
    const int colb = ocol + (ni << 4);
    const float bv = bias[colb];
#pragma unroll
    for (int mi = 0; mi < 4; ++mi) {
#pragma unroll
      for (int r = 0; r < 4; ++r) {
        float v = acc[mi][ni][r] + bv;
        if (ACT) v = 1.0f / (1.0f + expf(-v));
        const size_t off = (size_t)(orow + (mi << 4) + r) * N + colb;
        if (OUTBF) ((__bf16*)Cp)[off] = (__bf16)v;
        else       ((float*)Cp)[off] = v;
      }
    }
  }
}

// ---------------- r1: ksum/qsum over L ----------------
__global__ __launch_bounds__(256) void r1_sums(const __bf16* __restrict__ Qp, const __bf16* __restrict__ Kp,
                                               float* __restrict__ ksum, float* __restrict__ qsum) {
  const int blk = blockIdx.x;
  const int chunk = blk & 15, bh = blk >> 4;
  const int b = bh >> 4, h = bh & 15;
  const int d = threadIdx.x & 63, rs = threadIdx.x >> 6;
  const size_t base = ((size_t)b * Lc) * Dc + h * 64 + d;
  float ka = 0.f, qa = 0.f;
  const int l0 = chunk * 256;
  for (int i = rs; i < 256; i += 4) {
    const size_t idx = base + (size_t)(l0 + i) * Dc;
    ka += (float)Kp[idx];
    qa += (float)Qp[idx];
  }
  __shared__ float sk[256], sq[256];
  sk[threadIdx.x] = ka; sq[threadIdx.x] = qa;
  __syncthreads();
  if (threadIdx.x < 64) {
    float k4 = sk[d] + sk[64 + d] + sk[128 + d] + sk[192 + d];
    float q4 = sq[d] + sq[64 + d] + sq[128 + d] + sq[192 + d];
    atomicAdd(&ksum[bh * 64 + d], k4);
    atomicAdd(&qsum[bh * 64 + d], q4);
  }
}

// ---------------- r2: si/so + accumulate qsi/kso ----------------
__global__ __launch_bounds__(256) void r2_flow(const __bf16* __restrict__ Qp, const __bf16* __restrict__ Kp,
                                               const float* __restrict__ ksum, const float* __restrict__ qsum,
                                               float* __restrict__ si, float* __restrict__ so,
                                               float* __restrict__ qsi, float* __restrict__ kso) {
  const int blk = blockIdx.x;
  const int chunk = blk & 15, bh = blk >> 4;
  const int b = bh >> 4, h = bh & 15;
  const int d = threadIdx.x & 63, w = threadIdx.x >> 6;
  __shared__ float ksE[64], qsE[64];
  if (threadIdx.x < 64) ksE[threadIdx.x] = ksum[bh * 64 + threadIdx.x] + EPSc;
  else if (threadIdx.x < 128) qsE[threadIdx.x - 64] = qsum[bh * 64 + threadIdx.x - 64] + EPSc;
  __syncthreads();
  const float kE = ksE[d], qE = qsE[d];
  const size_t base = ((size_t)b * Lc) * Dc + h * 64 + d;
  const size_t obase = (size_t)bh * Lc;
  float qsia = 0.f, ksoa = 0.f;
  const int l0 = chunk * 256;
  for (int i = w; i < 256; i += 4) {
    const int l = l0 + i;
    const size_t idx = base + (size_t)l * Dc;
    const float qv = (float)Qp[idx], kvv = (float)Kp[idx];
    float a = (qv + EPSc) * kE;
    float c2 = (kvv + EPSc) * qE;
#pragma unroll
    for (int o = 32; o; o >>= 1) { a += __shfl_xor(a, o); c2 += __shfl_xor(c2, o); }
    const float sil = 1.0f / a, sol = 1.0f / c2;
    if (d == 0) { si[obase + l] = sil; so[obase + l] = sol; }
    qsia += qv * sil;
    ksoa += kvv * sol;
  }
  atomicAdd(&qsi[bh * 64 + d], qsia);
  atomicAdd(&kso[bh * 64 + d], ksoa);
}

// ---------------- r3: sink_allocation + clipped conserved_source ----------------
__global__ __launch_bounds__(256) void r3_cons(const __bf16* __restrict__ Qp, const __bf16* __restrict__ Kp,
                                               const float* __restrict__ qsi, const float* __restrict__ kso,
                                               float* __restrict__ sa, float* __restrict__ cs) {
  const int blk = blockIdx.x;
  const int chunk = blk & 15, bh = blk >> 4;
  const int b = bh >> 4, h = bh & 15;
  const int d = threadIdx.x & 63, w = threadIdx.x >> 6;
  __shared__ float ksoE[64], qsiE[64];
  if (threadIdx.x < 64) ksoE[threadIdx.x] = kso[bh * 64 + threadIdx.x] + EPSc;
  else if (threadIdx.x < 128) qsiE[threadIdx.x - 64] = qsi[bh * 64 + threadIdx.x - 64] + EPSc;
  __syncthreads();
  const float kE = ksoE[d], qE = qsiE[d];
  const size_t base = ((size_t)b * Lc) * Dc + h * 64 + d;
  const size_t obase = (size_t)bh * Lc;
  const int l0 = chunk * 256;
  for (int i = w; i < 256; i += 4) {
    const int l = l0 + i;
    const size_t idx = base + (size_t)l * Dc;
    const float qv = (float)Qp[idx], kvv = (float)Kp[idx];
    float a = (qv + EPSc) * kE;
    float c2 = (kvv + EPSc) * qE;
#pragma unroll
    for (int o = 32; o; o >>= 1) { a += __shfl_xor(a, o); c2 += __shfl_xor(c2, o); }
    if (d == 0) {
      sa[obase + l] = 1.0f / (1.0f + expf(-a));
      cs[obase + l] = fminf(1.0f, fmaxf(-1.0f, c2));
    }
  }
}

// ---------------- r4: softmax stats over L per (b,h) ----------------
__global__ __launch_bounds__(256) void r4_softmax(const float* __restrict__ cs,
                                                  float* __restrict__ mx, float* __restrict__ invden) {
  const int bh = blockIdx.x;
  const int tid = threadIdx.x;
  const float* c = cs + (size_t)bh * Lc;
  float m = -1e30f;
  for (int i = tid; i < Lc; i += 256) m = fmaxf(m, c[i]);
#pragma unroll
  for (int o = 32; o; o >>= 1) m = fmaxf(m, __shfl_xor(m, o));
  __shared__ float sm[4];
  if ((tid & 63) == 0) sm[tid >> 6] = m;
  __syncthreads();
  m = fmaxf(fmaxf(sm[0], sm[1]), fmaxf(sm[2], sm[3]));
  float s = 0.f;
  for (int i = tid; i < Lc; i += 256) s += expf(c[i] - m);
#pragma unroll
  for (int o = 32; o; o >>= 1) s += __shfl_xor(s, o);
  __shared__ float ss[4];
  if ((tid & 63) == 0) ss[tid >> 6] = s;
  __syncthreads();
  if (tid == 0) {
    s = ss[0] + ss[1] + ss[2] + ss[3];
    mx[bh] = m;
    invden[bh] = 1.0f / s;
  }
}

// ---------------- k5: kv[bh][d][m] = sum_l k * (v * scomp) ----------------
__global__ __launch_bounds__(256) void k5_kv(const __bf16* __restrict__ Kp, const __bf16* __restrict__ Vp,
                                             const float* __restrict__ cs, const float* __restrict__ mxb,
                                             const float* __restrict__ idn, float* __restrict__ kvout) {
  const int bh = blockIdx.x, chunk = blockIdx.y;  // chunk of 512 rows
  const int b = bh >> 4, h = bh & 15;
  const int tid = threadIdx.x;
  const int dq = (tid >> 4) << 2;
  const int mq = (tid & 15) << 2;
  const float mval = mxb[bh];
  const float sden = idn[bh] * 4096.0f;
  __shared__ float klds[4][64], vlds[4][64];
  float acc[4][4] = {};
  const int r = tid >> 6, c = tid & 63;
  const size_t rowbase = ((size_t)b * Lc + chunk * 512) * Dc + h * 64;
  const size_t csbase = (size_t)bh * Lc + chunk * 512;
  for (int i = 0; i < 512; i += 4) {
    const size_t idx = rowbase + (size_t)(i + r) * Dc + c;
    const float sc = expf(cs[csbase + i + r] - mval) * sden;
    klds[r][c] = (float)Kp[idx];
    vlds[r][c] = (float)Vp[idx] * sc;
    __syncthreads();
#pragma unroll
    for (int rr = 0; rr < 4; ++rr) {
      float kr[4], vr[4];
#pragma unroll
      for (int j = 0; j < 4; ++j) { kr[j] = klds[rr][dq + j]; vr[j] = vlds[rr][mq + j]; }
#pragma unroll
      for (int a = 0; a < 4; ++a)
#pragma unroll
        for (int e = 0; e < 4; ++e) acc[a][e] += kr[a] * vr[e];
    }
    __syncthreads();
  }
#pragma unroll
  for (int a = 0; a < 4; ++a)
#pragma unroll
    for (int e = 0; e < 4; ++e)
      atomicAdd(&kvout[(size_t)bh * 4096 + (dq + a) * 64 + mq + e], acc[a][e]);
}

// ---------------- k6: x = (q*si) @ kv * sa, write bf16 ----------------
__global__ __launch_bounds__(256) void k6_x(const __bf16* __restrict__ Qp,
                                            const float* __restrict__ kvin, const float* __restrict__ si,
                                            const float* __restrict__ sa, __bf16* __restrict__ Xb) {
  const int bh = blockIdx.x, chunk = blockIdx.y;  // chunk of 256 rows
  const int b = bh >> 4, h = bh & 15;
  const int tid = threadIdx.x;
  __shared__ float kvs[4096];
  __shared__ float ql[64][65];
  for (int e = tid; e < 4096; e += 256) kvs[e] = kvin[(size_t)bh * 4096 + e];
  const int rr0 = (tid >> 4) << 2;
  const int mq = (tid & 15) << 2;
  const size_t bL = (size_t)b * Lc;
  const size_t obase = (size_t)bh * Lc;
  for (int g = 0; g < 4; ++g) {
    const int l0 = chunk * 256 + g * 64;
    __syncthreads();
    for (int e = tid; e < 4096; e += 256)
      ql[e >> 6][e & 63] = (float)Qp[(bL + l0 + (e >> 6)) * Dc + h * 64 + (e & 63)];
    __syncthreads();
    float acc[4][4] = {};
#pragma unroll
    for (int d = 0; d < 64; ++d) {
      float kvr[4], qr[4];
#pragma unroll
      for (int j = 0; j < 4; ++j) { qr[j] = ql[rr0 + j][d]; kvr[j] = kvs[d * 64 + mq + j]; }
#pragma unroll
      for (int a = 0; a < 4; ++a)
#pragma unroll
        for (int e = 0; e < 4; ++e) acc[a][e] += qr[a] * kvr[e];
    }
#pragma unroll
    for (int a = 0; a < 4; ++a) {
      const int l = l0 + rr0 + a;
      const float sc = si[obase + l] * sa[obase + l];
      bf16x4 o;
#pragma unroll
      for (int e = 0; e < 4; ++e) o[e] = (__bf16)(acc[a][e] * sc);
      *(bf16x4*)&Xb[(bL + l) * Dc + h * 64 + mq] = o;
    }
  }
}

// ---------------- host ----------------
extern "C" void kernel_launch(void* const* d_in, const int* in_sizes, int n_in,
                              void* d_out, int out_size, void* d_ws, size_t ws_size,
                              hipStream_t stream) {
  const float* Qin = (const float*)d_in[0];
  const float* Kin = (const float*)d_in[1];
  const float* Vin = (const float*)d_in[2];
  const float* Wq = (const float*)d_in[3];
  const float* bq = (const float*)d_in[4];
  const float* Wk = (const float*)d_in[5];
  const float* bk = (const float*)d_in[6];
  const float* Wv = (const float*)d_in[7];
  const float* bv = (const float*)d_in[8];
  const float* Wo = (const float*)d_in[9];
  const float* bo = (const float*)d_in[10];

  const size_t MD = (size_t)Mc * Dc;
  __bf16* Aq = (__bf16*)d_ws;
  __bf16* Ak = Aq + MD;
  __bf16* Av = Ak + MD;
  __bf16* Wqt = Av + MD;
  __bf16* Wkt = Wqt + (size_t)Dc * Dc;
  __bf16* Wvt = Wkt + (size_t)Dc * Dc;
  __bf16* Wot = Wvt + (size_t)Dc * Dc;
  __bf16* Qp = Wot + (size_t)Dc * Dc;
  __bf16* Kp = Qp + MD;
  __bf16* Vp = Kp + MD;
  float* F = (float*)(Vp + MD);
  float* ksum = F;
  float* qsum = ksum + 4096;
  float* kso = qsum + 4096;
  float* qsi = kso + 4096;
  float* kv = qsi + 4096;       // 64*4096
  float* si = kv + 262144;
  float* so = si + 262144;
  float* sa = so + 262144;
  float* cs = sa + 262144;
  float* mxb = cs + 262144;     // 64
  float* idn = mxb + 64;        // 64
  __bf16* Xb = Aq;              // reuse Aq (dead after first GEMM)

  hipMemsetAsync(F, 0, (size_t)(4 * 4096 + 262144) * sizeof(float), stream);

  const int n4blocks = (int)(MD / 4 / 256);
  conv_bf16<<<n4blocks, 256, 0, stream>>>(Qin, Aq);
  conv_bf16<<<n4blocks, 256, 0, stream>>>(Kin, Ak);
  conv_bf16<<<n4blocks, 256, 0, stream>>>(Vin, Av);
  dim3 wtg(32, 32), wtb(32, 8);
  wt_conv<<<wtg, wtb, 0, stream>>>(Wq, Wqt);
  wt_conv<<<wtg, wtb, 0, stream>>>(Wk, Wkt);
  wt_conv<<<wtg, wtb, 0, stream>>>(Wv, Wvt);
  wt_conv<<<wtg, wtb, 0, stream>>>(Wo, Wot);

  dim3 gg(Mc / 128, Dc / 128);
  gemm_bt<1, 1><<<gg, 256, 0, stream>>>(Aq, Wqt, bq, Qp, Mc, Dc, Dc);
  gemm_bt<1, 1><<<gg, 256, 0, stream>>>(Ak, Wkt, bk, Kp, Mc, Dc, Dc);
  gemm_bt<0, 1><<<gg, 256, 0, stream>>>(Av, Wvt, bv, Vp, Mc, Dc, Dc);

  r1_sums<<<1024, 256, 0, stream>>>(Qp, Kp, ksum, qsum);
  r2_flow<<<1024, 256, 0, stream>>>(Qp, Kp, ksum, qsum, si, so, qsi, kso);
  r3_cons<<<1024, 256, 0, stream>>>(Qp, Kp, qsi, kso, sa, cs);
  r4_softmax<<<64, 256, 0, stream>>>(cs, mxb, idn);
  k5_kv<<<dim3(64, 8), 256, 0, stream>>>(Kp, Vp, cs, mxb, idn, kv);
  k6_x<<<dim3(64, 16), 256, 0, stream>>>(Qp, kv, si, sa, Xb);

  gemm_bt<0, 0><<<gg, 256, 0, stream>>>(Xb, Wot, bo, d_out, Mc, Dc, Dc);
}

// Round 2
// 552.501 us; speedup vs baseline: 1.0151x; 1.0151x over previous
//
#include <hip/hip_runtime.h>

#define Bc 4
#define Lc 4096
#define Dc 1024
#define Mc (Bc*Lc)
#define EPSc 1e-6f

typedef __bf16 bf16x8 __attribute__((ext_vector_type(8)));
typedef __bf16 bf16x4 __attribute__((ext_vector_type(4)));
typedef float f32x4 __attribute__((ext_vector_type(4)));

typedef __attribute__((address_space(3))) void lds_vt;
typedef const __attribute__((address_space(1))) void gbl_vt;

__device__ __forceinline__ void gll16(const void* g, void* l) {
  __builtin_amdgcn_global_load_lds((gbl_vt*)g, (lds_vt*)l, 16, 0, 0);
}

// ---------------- converts ----------------
__global__ __launch_bounds__(256) void conv_bf16(const float* __restrict__ X, __bf16* __restrict__ Y) {
  const int i = blockIdx.x * 256 + threadIdx.x;
  const float4 v = ((const float4*)X)[i];
  bf16x4 o;
  o[0] = (__bf16)v.x; o[1] = (__bf16)v.y; o[2] = (__bf16)v.z; o[3] = (__bf16)v.w;
  ((bf16x4*)Y)[i] = o;
}

__global__ __launch_bounds__(256) void wt_conv(const float* __restrict__ W, __bf16* __restrict__ Wt) {
  __shared__ float t[32][33];
  const int n0 = blockIdx.x << 5, k0 = blockIdx.y << 5;
  const int tx = threadIdx.x, ty = threadIdx.y;  // block (32,8)
#pragma unroll
  for (int i = 0; i < 4; ++i)
    t[ty + 8 * i][tx] = W[(size_t)(k0 + ty + 8 * i) * Dc + n0 + tx];
  __syncthreads();
#pragma unroll
  for (int i = 0; i < 4; ++i)
    Wt[(size_t)(n0 + ty + 8 * i) * Dc + k0 + tx] = (__bf16)t[tx][ty + 8 * i];
}

// ---------------- GEMM 256x256, BK=32, 4-deep ring, counted vmcnt ----------------
// C[M,N] = act(A[M,K] @ Bt[N,K]^T + bias); optional column-sum atomics (r1 fusion).
template <int ACT, int OUTBF, int SUMF>
__global__ __launch_bounds__(512, 2) void gemm256(
    const __bf16* __restrict__ A, const __bf16* __restrict__ Bt,
    const float* __restrict__ bias, void* __restrict__ Cp,
    float* __restrict__ sums, int M, int N, int K) {
  __shared__ __bf16 As[4][8192];
  __shared__ __bf16 Bs[4][8192];
  const int tid = threadIdx.x;
  const int lane = tid & 63, wid = tid >> 6;
  const int wr = wid >> 2, wc = wid & 3;       // 2 x 4 waves
  const int row0 = blockIdx.x << 8, col0 = blockIdx.y << 8;

  // staging: slot s (0..1023 granules of 16B) -> row=s>>2; pre-swizzled source kg
  const int s0 = tid, s1 = tid + 512;
  const int r0 = s0 >> 2, r1s = s1 >> 2;
  const int c0 = (((s0 & 3) ^ ((s0 >> 3) & 3)) << 3);
  const int c1 = (((s1 & 3) ^ ((s1 >> 3) & 3)) << 3);
  const size_t aoff0 = (size_t)(row0 + r0) * K + c0;
  const size_t aoff1 = (size_t)(row0 + r1s) * K + c1;
  const size_t boff0 = (size_t)(col0 + r0) * K + c0;
  const size_t boff1 = (size_t)(col0 + r1s) * K + c1;
  const int d0 = s0 << 3, d1 = s1 << 3;        // linear LDS element offsets

#define STG(t, u) do { \
    const int kb_ = (t) << 5; \
    gll16(A + aoff0 + kb_, &As[u][d0]); \
    gll16(A + aoff1 + kb_, &As[u][d1]); \
    gll16(Bt + boff0 + kb_, &Bs[u][d0]); \
    gll16(Bt + boff1 + kb_, &Bs[u][d1]); \
  } while (0)

  // swizzled read offsets: row = base + (lane&15), kgroup = lane>>4
  const int lf = lane & 15;
  const int kgp = (lane >> 4) ^ ((lf >> 1) & 3);
  const int abase = (wr * 128 + lf) * 32 + (kgp << 3);
  const int bbase = (wc * 64 + lf) * 32 + (kgp << 3);

  f32x4 acc[8][4] = {};
  const int NT = K >> 5;

  STG(0, 0); STG(1, 1); STG(2, 2);
  asm volatile("s_waitcnt vmcnt(8)" ::: "memory");
  asm volatile("s_barrier" ::: "memory");

  for (int t = 0; t < NT; ++t) {
    if (t + 3 < NT) STG(t + 3, (t + 3) & 3);
    const __bf16* Ab = As[t & 3];
    const __bf16* Bb = Bs[t & 3];
    bf16x8 af[8], bfr[4];
#pragma unroll
    for (int mi = 0; mi < 8; ++mi) af[mi] = *(const bf16x8*)(Ab + abase + mi * 512);
#pragma unroll
    for (int ni = 0; ni < 4; ++ni) bfr[ni] = *(const bf16x8*)(Bb + bbase + ni * 512);
    __builtin_amdgcn_s_setprio(1);
#pragma unroll
    for (int mi = 0; mi < 8; ++mi)
#pragma unroll
      for (int ni = 0; ni < 4; ++ni)
        acc[mi][ni] = __builtin_amdgcn_mfma_f32_16x16x32_bf16(af[mi], bfr[ni], acc[mi][ni], 0, 0, 0);
    __builtin_amdgcn_s_setprio(0);
    if (t + 3 < NT)       asm volatile("s_waitcnt vmcnt(8)" ::: "memory");
    else if (t + 3 == NT) asm volatile("s_waitcnt vmcnt(4)" ::: "memory");
    else if (t + 2 == NT) asm volatile("s_waitcnt vmcnt(0)" ::: "memory");
    asm volatile("s_waitcnt lgkmcnt(0)" ::: "memory");
    asm volatile("s_barrier" ::: "memory");
  }
#undef STG

  // epilogue: C row=(lane>>4)*4+r (+mi*16), col=lane&15 (+ni*16)
  const int b_of = row0 >> 12;                 // batch index (rows 4096-aligned)
  const int orow = row0 + wr * 128 + ((lane >> 4) << 2);
  const int ocol = col0 + wc * 64 + lf;
#pragma unroll
  for (int ni = 0; ni < 4; ++ni) {
    const int colb = ocol + (ni << 4);
    const float bv = bias[colb];
    float ps = 0.f;
#pragma unroll
    for (int mi = 0; mi < 8; ++mi) {
#pragma unroll
      for (int r = 0; r < 4; ++r) {
        float v = acc[mi][ni][r] + bv;
        if (ACT) v = 1.0f / (1.0f + expf(-v));
        if (SUMF) ps += v;
        const size_t off = (size_t)(orow + (mi << 4) + r) * N + colb;
        if (OUTBF) ((__bf16*)Cp)[off] = (__bf16)v;
        else       ((float*)Cp)[off] = v;
      }
    }
    if (SUMF) atomicAdd(&sums[b_of * 1024 + colb], ps);
  }
}

// ---------------- r2: si/so + accumulate qsi/kso ----------------
__global__ __launch_bounds__(256) void r2_flow(const __bf16* __restrict__ Qp, const __bf16* __restrict__ Kp,
                                               const float* __restrict__ ksum, const float* __restrict__ qsum,
                                               float* __restrict__ si, float* __restrict__ so,
                                               float* __restrict__ qsi, float* __restrict__ kso) {
  const int blk = blockIdx.x;
  const int chunk = blk & 15, bh = blk >> 4;
  const int b = bh >> 4, h = bh & 15;
  const int d = threadIdx.x & 63, w = threadIdx.x >> 6;
  __shared__ float ksE[64], qsE[64];
  if (threadIdx.x < 64) ksE[threadIdx.x] = ksum[bh * 64 + threadIdx.x] + EPSc;
  else if (threadIdx.x < 128) qsE[threadIdx.x - 64] = qsum[bh * 64 + threadIdx.x - 64] + EPSc;
  __syncthreads();
  const float kE = ksE[d], qE = qsE[d];
  const size_t base = ((size_t)b * Lc) * Dc + h * 64 + d;
  const size_t obase = (size_t)bh * Lc;
  float qsia = 0.f, ksoa = 0.f;
  const int l0 = chunk * 256;
  for (int i = w; i < 256; i += 4) {
    const int l = l0 + i;
    const size_t idx = base + (size_t)l * Dc;
    const float qv = (float)Qp[idx], kvv = (float)Kp[idx];
    float a = (qv + EPSc) * kE;
    float c2 = (kvv + EPSc) * qE;
#pragma unroll
    for (int o = 32; o; o >>= 1) { a += __shfl_xor(a, o); c2 += __shfl_xor(c2, o); }
    const float sil = 1.0f / a, sol = 1.0f / c2;
    if (d == 0) { si[obase + l] = sil; so[obase + l] = sol; }
    qsia += qv * sil;
    ksoa += kvv * sol;
  }
  atomicAdd(&qsi[bh * 64 + d], qsia);
  atomicAdd(&kso[bh * 64 + d], ksoa);
}

// ---------------- r3: sink_allocation + exp(clipped conserved_source) + denom ----------------
__global__ __launch_bounds__(256) void r3_cons(const __bf16* __restrict__ Qp, const __bf16* __restrict__ Kp,
                                               const float* __restrict__ qsi, const float* __restrict__ kso,
                                               float* __restrict__ sa, float* __restrict__ csx,
                                               float* __restrict__ den) {
  const int blk = blockIdx.x;
  const int chunk = blk & 15, bh = blk >> 4;
  const int b = bh >> 4, h = bh & 15;
  const int d = threadIdx.x & 63, w = threadIdx.x >> 6;
  __shared__ float ksoE[64], qsiE[64];
  if (threadIdx.x < 64) ksoE[threadIdx.x] = kso[bh * 64 + threadIdx.x] + EPSc;
  else if (threadIdx.x < 128) qsiE[threadIdx.x - 64] = qsi[bh * 64 + threadIdx.x - 64] + EPSc;
  __syncthreads();
  const float kE = ksoE[d], qE = qsiE[d];
  const size_t base = ((size_t)b * Lc) * Dc + h * 64 + d;
  const size_t obase = (size_t)bh * Lc;
  const int l0 = chunk * 256;
  float eacc = 0.f;
  for (int i = w; i < 256; i += 4) {
    const int l = l0 + i;
    const size_t idx = base + (size_t)l * Dc;
    const float qv = (float)Qp[idx], kvv = (float)Kp[idx];
    float a = (qv + EPSc) * kE;
    float c2 = (kvv + EPSc) * qE;
#pragma unroll
    for (int o = 32; o; o >>= 1) { a += __shfl_xor(a, o); c2 += __shfl_xor(c2, o); }
    if (d == 0) {
      sa[obase + l] = 1.0f / (1.0f + expf(-a));
      const float cl = fminf(1.0f, fmaxf(-1.0f, c2));
      const float e = expf(cl);          // max-free softmax: cl in [-1,1]
      csx[obase + l] = e;
      eacc += e;
    }
  }
  if (d == 0) atomicAdd(&den[bh], eacc);
}

// ---------------- k5: kv[bh][d][m] = sum_l k * (v * scomp) ----------------
__global__ __launch_bounds__(256) void k5_kv(const __bf16* __restrict__ Kp, const __bf16* __restrict__ Vp,
                                             const float* __restrict__ csx, const float* __restrict__ den,
                                             float* __restrict__ kvout) {
  const int bh = blockIdx.x, chunk = blockIdx.y;  // chunk of 512 rows
  const int b = bh >> 4, h = bh & 15;
  const int tid = threadIdx.x;
  const int dq = (tid >> 4) << 2;
  const int mq = (tid & 15) << 2;
  const float sden = 4096.0f / den[bh];
  __shared__ float klds[4][64], vlds[4][64];
  float acc[4][4] = {};
  const int r = tid >> 6, c = tid & 63;
  const size_t rowbase = ((size_t)b * Lc + chunk * 512) * Dc + h * 64;
  const size_t csbase = (size_t)bh * Lc + chunk * 512;
  for (int i = 0; i < 512; i += 4) {
    const size_t idx = rowbase + (size_t)(i + r) * Dc + c;
    const float sc = csx[csbase + i + r] * sden;
    klds[r][c] = (float)Kp[idx];
    vlds[r][c] = (float)Vp[idx] * sc;
    __syncthreads();
#pragma unroll
    for (int rr = 0; rr < 4; ++rr) {
      float kr[4], vr[4];
#pragma unroll
      for (int j = 0; j < 4; ++j) { kr[j] = klds[rr][dq + j]; vr[j] = vlds[rr][mq + j]; }
#pragma unroll
      for (int a = 0; a < 4; ++a)
#pragma unroll
        for (int e = 0; e < 4; ++e) acc[a][e] += kr[a] * vr[e];
    }
    __syncthreads();
  }
#pragma unroll
  for (int a = 0; a < 4; ++a)
#pragma unroll
    for (int e = 0; e < 4; ++e)
      atomicAdd(&kvout[(size_t)bh * 4096 + (dq + a) * 64 + mq + e], acc[a][e]);
}

// ---------------- k6: x = (q*si) @ kv * sa, write bf16 ----------------
__global__ __launch_bounds__(256) void k6_x(const __bf16* __restrict__ Qp,
                                            const float* __restrict__ kvin, const float* __restrict__ si,
                                            const float* __restrict__ sa, __bf16* __restrict__ Xb) {
  const int bh = blockIdx.x, chunk = blockIdx.y;  // chunk of 256 rows
  const int b = bh >> 4, h = bh & 15;
  const int tid = threadIdx.x;
  __shared__ float kvs[4096];
  __shared__ float ql[64][65];
  for (int e = tid; e < 4096; e += 256) kvs[e] = kvin[(size_t)bh * 4096 + e];
  const int rr0 = (tid >> 4) << 2;
  const int mq = (tid & 15) << 2;
  const size_t bL = (size_t)b * Lc;
  const size_t obase = (size_t)bh * Lc;
  for (int g = 0; g < 4; ++g) {
    const int l0 = chunk * 256 + g * 64;
    __syncthreads();
    for (int e = tid; e < 4096; e += 256)
      ql[e >> 6][e & 63] = (float)Qp[(bL + l0 + (e >> 6)) * Dc + h * 64 + (e & 63)];
    __syncthreads();
    float acc[4][4] = {};
#pragma unroll
    for (int d = 0; d < 64; ++d) {
      float kvr[4], qr[4];
#pragma unroll
      for (int j = 0; j < 4; ++j) { qr[j] = ql[rr0 + j][d]; kvr[j] = kvs[d * 64 + mq + j]; }
#pragma unroll
      for (int a = 0; a < 4; ++a)
#pragma unroll
        for (int e = 0; e < 4; ++e) acc[a][e] += qr[a] * kvr[e];
    }
#pragma unroll
    for (int a = 0; a < 4; ++a) {
      const int l = l0 + rr0 + a;
      const float sc = si[obase + l] * sa[obase + l];
      bf16x4 o;
#pragma unroll
      for (int e = 0; e < 4; ++e) o[e] = (__bf16)(acc[a][e] * sc);
      *(bf16x4*)&Xb[(bL + l) * Dc + h * 64 + mq] = o;
    }
  }
}

// ---------------- host ----------------
extern "C" void kernel_launch(void* const* d_in, const int* in_sizes, int n_in,
                              void* d_out, int out_size, void* d_ws, size_t ws_size,
                              hipStream_t stream) {
  const float* Qin = (const float*)d_in[0];
  const float* Kin = (const float*)d_in[1];
  const float* Vin = (const float*)d_in[2];
  const float* Wq = (const float*)d_in[3];
  const float* bq = (const float*)d_in[4];
  const float* Wk = (const float*)d_in[5];
  const float* bk = (const float*)d_in[6];
  const float* Wv = (const float*)d_in[7];
  const float* bv = (const float*)d_in[8];
  const float* Wo = (const float*)d_in[9];
  const float* bo = (const float*)d_in[10];

  const size_t MD = (size_t)Mc * Dc;
  __bf16* Aq = (__bf16*)d_ws;
  __bf16* Ak = Aq + MD;
  __bf16* Av = Ak + MD;
  __bf16* Wqt = Av + MD;
  __bf16* Wkt = Wqt + (size_t)Dc * Dc;
  __bf16* Wvt = Wkt + (size_t)Dc * Dc;
  __bf16* Wot = Wvt + (size_t)Dc * Dc;
  __bf16* Qp = Wot + (size_t)Dc * Dc;
  __bf16* Kp = Qp + MD;
  __bf16* Vp = Kp + MD;
  float* F = (float*)(Vp + MD);
  float* ksum = F;              // 4096
  float* qsum = ksum + 4096;    // 4096
  float* kso = qsum + 4096;     // 4096
  float* qsi = kso + 4096;      // 4096
  float* den = qsi + 4096;      // 64
  float* kv = den + 64;         // 64*4096
  float* si = kv + 262144;
  float* so = si + 262144;
  float* sa = so + 262144;
  float* csx = sa + 262144;
  __bf16* Xb = Aq;              // reuse Aq (dead after Q-GEMM)

  hipMemsetAsync(F, 0, (size_t)(4 * 4096 + 64 + 262144) * sizeof(float), stream);

  const int n4blocks = (int)(MD / 4 / 256);
  conv_bf16<<<n4blocks, 256, 0, stream>>>(Qin, Aq);
  conv_bf16<<<n4blocks, 256, 0, stream>>>(Kin, Ak);
  conv_bf16<<<n4blocks, 256, 0, stream>>>(Vin, Av);
  dim3 wtg(32, 32), wtb(32, 8);
  wt_conv<<<wtg, wtb, 0, stream>>>(Wq, Wqt);
  wt_conv<<<wtg, wtb, 0, stream>>>(Wk, Wkt);
  wt_conv<<<wtg, wtb, 0, stream>>>(Wv, Wvt);
  wt_conv<<<wtg, wtb, 0, stream>>>(Wo, Wot);

  dim3 gg(Mc / 256, Dc / 256);
  gemm256<1, 1, 1><<<gg, 512, 0, stream>>>(Aq, Wqt, bq, Qp, qsum, Mc, Dc, Dc);
  gemm256<1, 1, 1><<<gg, 512, 0, stream>>>(Ak, Wkt, bk, Kp, ksum, Mc, Dc, Dc);
  gemm256<0, 1, 0><<<gg, 512, 0, stream>>>(Av, Wvt, bv, Vp, nullptr, Mc, Dc, Dc);

  r2_flow<<<1024, 256, 0, stream>>>(Qp, Kp, ksum, qsum, si, so, qsi, kso);
  r3_cons<<<1024, 256, 0, stream>>>(Qp, Kp, qsi, kso, sa, csx, den);
  k5_kv<<<dim3(64, 8), 256, 0, stream>>>(Kp, Vp, csx, den, kv);
  k6_x<<<dim3(64, 16), 256, 0, stream>>>(Qp, kv, si, sa, Xb);

  gemm256<0, 0, 0><<<gg, 512, 0, stream>>>(Xb, Wot, bo, d_out, nullptr, Mc, Dc, Dc);
}

// Round 3
// 549.224 us; speedup vs baseline: 1.0212x; 1.0060x over previous
//
#include <hip/hip_runtime.h>

#define Bc 4
#define Lc 4096
#define Dc 1024
#define Mc (Bc*Lc)
#define EPSc 1e-6f

typedef __bf16 bf16x8 __attribute__((ext_vector_type(8)));
typedef __bf16 bf16x4 __attribute__((ext_vector_type(4)));
typedef float f32x4 __attribute__((ext_vector_type(4)));

typedef __attribute__((address_space(3))) void lds_vt;
typedef const __attribute__((address_space(1))) void gbl_vt;

__device__ __forceinline__ void gll16(const void* g, void* l) {
  __builtin_amdgcn_global_load_lds((gbl_vt*)g, (lds_vt*)l, 16, 0, 0);
}

// ---------------- converts ----------------
__global__ __launch_bounds__(256) void conv_bf16(const float* __restrict__ X, __bf16* __restrict__ Y) {
  const int i = blockIdx.x * 256 + threadIdx.x;
  const float4 v = ((const float4*)X)[i];
  bf16x4 o;
  o[0] = (__bf16)v.x; o[1] = (__bf16)v.y; o[2] = (__bf16)v.z; o[3] = (__bf16)v.w;
  ((bf16x4*)Y)[i] = o;
}

__global__ __launch_bounds__(256) void wt_conv(const float* __restrict__ W, __bf16* __restrict__ Wt) {
  __shared__ float t[32][33];
  const int n0 = blockIdx.x << 5, k0 = blockIdx.y << 5;
  const int tx = threadIdx.x, ty = threadIdx.y;  // block (32,8)
#pragma unroll
  for (int i = 0; i < 4; ++i)
    t[ty + 8 * i][tx] = W[(size_t)(k0 + ty + 8 * i) * Dc + n0 + tx];
  __syncthreads();
#pragma unroll
  for (int i = 0; i < 4; ++i)
    Wt[(size_t)(n0 + ty + 8 * i) * Dc + k0 + tx] = (__bf16)t[tx][ty + 8 * i];
}

// ---------------- GEMM 256x256, BK=64, dbuf, 4-phase interleave, counted vmcnt ----------------
// C[M,N] = act(A[M,K] @ Bt[N,K]^T + bias); optional column-sum atomics.
// LDS layout per buffer: [row][64] bf16, granule(16B) swizzle kg ^= (row&7),
// applied as pre-swizzled global SOURCE + swizzled ds_read (linear gll16 dest).
template <int ACT, int OUTBF, int SUMF>
__global__ __launch_bounds__(512, 2) void gemm256(
    const __bf16* __restrict__ A, const __bf16* __restrict__ Bt,
    const float* __restrict__ bias, void* __restrict__ Cp,
    float* __restrict__ sums, int M, int N, int K) {
  __shared__ __bf16 As[2][16384];
  __shared__ __bf16 Bs[2][16384];
  const int tid = threadIdx.x;
  const int lane = tid & 63, w8 = tid >> 6;
  const int wr = w8 >> 2, wc = w8 & 3;          // 2 x 4 waves
  const int row0 = blockIdx.x << 8, col0 = blockIdx.y << 8;
  const int lf = lane & 15, kq = lane >> 4, xr = lf & 7;

  // fragment read bases (element offsets); kgN = swizzled 8-elem k-granule for kk=N
  const int abase = (wr * 128 + lf) * 64;
  const int bbase = (wc * 64 + lf) * 64;
  const int kg0 = (kq ^ xr) << 3;
  const int kg1 = ((4 + kq) ^ xr) << 3;

  // Staging groups (2 gll16/thread each): g0=A-early rows{0-63,128-191},
  // g1=B-early rows{0-31,64-95,128-159,192-223}, g2=A-late(+64), g3=B-late(+32).
  // Dest is lane-linear per instruction (wave-uniform base + lane*16) as gll16 requires.
#define STG(G, T, U) do { \
    _Pragma("unroll") \
    for (int i_ = 0; i_ < 2; ++i_) { \
      const int j_ = w8 * 128 + i_ * 64 + lane; \
      const int re_ = j_ >> 3, kgd_ = j_ & 7; \
      if ((G) == 0 || (G) == 2) { \
        const int row_ = (re_ & 63) + ((re_ >> 6) << 7) + (((G) == 2) ? 64 : 0); \
        gll16(A + (size_t)(row0 + row_) * K + ((T) << 6) + ((kgd_ ^ (row_ & 7)) << 3), \
              &As[U][row_ * 64 + (kgd_ << 3)]); \
      } else { \
        const int row_ = (re_ & 31) + ((re_ >> 5) << 6) + (((G) == 3) ? 32 : 0); \
        gll16(Bt + (size_t)(col0 + row_) * K + ((T) << 6) + ((kgd_ ^ (row_ & 7)) << 3), \
              &Bs[U][row_ * 64 + (kgd_ << 3)]); \
      } \
    } \
  } while (0)

#define RDA(AFR, MB) _Pragma("unroll") for (int m_ = 0; m_ < 4; ++m_) { \
    AFR[m_][0] = *(const bf16x8*)(Ab + abase + ((MB) + m_) * 1024 + kg0); \
    AFR[m_][1] = *(const bf16x8*)(Ab + abase + ((MB) + m_) * 1024 + kg1); }
#define RDB(BFR, NB) _Pragma("unroll") for (int n_ = 0; n_ < 2; ++n_) { \
    BFR[n_][0] = *(const bf16x8*)(Bb + bbase + ((NB) + n_) * 1024 + kg0); \
    BFR[n_][1] = *(const bf16x8*)(Bb + bbase + ((NB) + n_) * 1024 + kg1); }
#define MM(MB, NB, AFR, BFR) _Pragma("unroll") for (int m_ = 0; m_ < 4; ++m_) \
    _Pragma("unroll") for (int n_ = 0; n_ < 2; ++n_) \
    _Pragma("unroll") for (int k_ = 0; k_ < 2; ++k_) \
      acc[(MB) + m_][(NB) + n_] = __builtin_amdgcn_mfma_f32_16x16x32_bf16( \
          AFR[m_][k_], BFR[n_][k_], acc[(MB) + m_][(NB) + n_], 0, 0, 0);
#define BARx __builtin_amdgcn_s_barrier()
#define LGKM0 do { asm volatile("s_waitcnt lgkmcnt(0)" ::: "memory"); \
                   __builtin_amdgcn_sched_barrier(0); } while (0)
#define PRIO1 __builtin_amdgcn_s_setprio(1)
#define PRIO0 __builtin_amdgcn_s_setprio(0)

  f32x4 acc[8][4] = {};
  const int NT = K >> 6;

  // prologue: stage tile 0 into buf 0; need g0,g1 landed before P0 reads
  STG(0, 0, 0); STG(1, 0, 0); STG(2, 0, 0); STG(3, 0, 0);
  asm volatile("s_waitcnt vmcnt(4)" ::: "memory");
  BARx;

  for (int t = 0; t < NT - 1; ++t) {
    const __bf16* Ab = As[t & 1];
    const __bf16* Bb = Bs[t & 1];
    const int u = (t & 1) ^ 1;
    bf16x8 af0[4][2], af1[4][2], bfr[2][2];
    // P0: m0-3 x n0-1
    STG(0, t + 1, u);
    RDA(af0, 0) RDB(bfr, 0)
    BARx; LGKM0;
    PRIO1; MM(0, 0, af0, bfr) PRIO0;
    asm volatile("s_waitcnt vmcnt(4)" ::: "memory"); BARx;
    // P1: m4-7 x n0-1
    STG(1, t + 1, u);
    RDA(af1, 4)
    BARx; LGKM0;
    PRIO1; MM(4, 0, af1, bfr) PRIO0;
    asm volatile("s_waitcnt vmcnt(4)" ::: "memory"); BARx;
    // P2: m0-3 x n2-3
    STG(2, t + 1, u);
    RDB(bfr, 2)
    BARx; LGKM0;
    PRIO1; MM(0, 2, af0, bfr) PRIO0;
    BARx;
    // P3: m4-7 x n2-3
    STG(3, t + 1, u);
    BARx;
    PRIO1; MM(4, 2, af1, bfr) PRIO0;
    asm volatile("s_waitcnt vmcnt(4)" ::: "memory"); BARx;
  }
  {  // peeled last tile: drains 4 -> 2 -> 0
    const __bf16* Ab = As[(NT - 1) & 1];
    const __bf16* Bb = Bs[(NT - 1) & 1];
    bf16x8 af0[4][2], af1[4][2], bfr[2][2];
    RDA(af0, 0) RDB(bfr, 0)
    BARx; LGKM0;
    PRIO1; MM(0, 0, af0, bfr) PRIO0;
    asm volatile("s_waitcnt vmcnt(2)" ::: "memory"); BARx;
    RDA(af1, 4)
    BARx; LGKM0;
    PRIO1; MM(4, 0, af1, bfr) PRIO0;
    asm volatile("s_waitcnt vmcnt(0)" ::: "memory"); BARx;
    RDB(bfr, 2)
    BARx; LGKM0;
    PRIO1; MM(0, 2, af0, bfr) PRIO0;
    BARx;
    PRIO1; MM(4, 2, af1, bfr) PRIO0;
  }
#undef STG
#undef RDA
#undef RDB
#undef MM

  // epilogue: C row=(lane>>4)*4+r (+mi*16), col=lane&15 (+ni*16)
  const int b_of = row0 >> 12;
  const int orow = row0 + wr * 128 + ((lane >> 4) << 2);
  const int ocol = col0 + wc * 64 + lf;
#pragma unroll
  for (int ni = 0; ni < 4; ++ni) {
    const int colb = ocol + (ni << 4);
    const float bv = bias[colb];
    float ps = 0.f;
#pragma unroll
    for (int mi = 0; mi < 8; ++mi) {
#pragma unroll
      for (int r = 0; r < 4; ++r) {
        float v = acc[mi][ni][r] + bv;
        if (ACT) v = 1.0f / (1.0f + expf(-v));
        if (SUMF) ps += v;
        const size_t off = (size_t)(orow + (mi << 4) + r) * N + colb;
        if (OUTBF) ((__bf16*)Cp)[off] = (__bf16)v;
        else       ((float*)Cp)[off] = v;
      }
    }
    if (SUMF) atomicAdd(&sums[b_of * 1024 + colb], ps);
  }
}

// ---------------- r2: si/so + accumulate qsi/kso ----------------
__global__ __launch_bounds__(256) void r2_flow(const __bf16* __restrict__ Qp, const __bf16* __restrict__ Kp,
                                               const float* __restrict__ ksum, const float* __restrict__ qsum,
                                               float* __restrict__ si, float* __restrict__ so,
                                               float* __restrict__ qsi, float* __restrict__ kso) {
  const int blk = blockIdx.x;
  const int chunk = blk & 15, bh = blk >> 4;
  const int b = bh >> 4, h = bh & 15;
  const int d = threadIdx.x & 63, w = threadIdx.x >> 6;
  __shared__ float ksE[64], qsE[64];
  if (threadIdx.x < 64) ksE[threadIdx.x] = ksum[bh * 64 + threadIdx.x] + EPSc;
  else if (threadIdx.x < 128) qsE[threadIdx.x - 64] = qsum[bh * 64 + threadIdx.x - 64] + EPSc;
  __syncthreads();
  const float kE = ksE[d], qE = qsE[d];
  const size_t base = ((size_t)b * Lc) * Dc + h * 64 + d;
  const size_t obase = (size_t)bh * Lc;
  float qsia = 0.f, ksoa = 0.f;
  const int l0 = chunk * 256;
  for (int i = w; i < 256; i += 4) {
    const int l = l0 + i;
    const size_t idx = base + (size_t)l * Dc;
    const float qv = (float)Qp[idx], kvv = (float)Kp[idx];
    float a = (qv + EPSc) * kE;
    float c2 = (kvv + EPSc) * qE;
#pragma unroll
    for (int o = 32; o; o >>= 1) { a += __shfl_xor(a, o); c2 += __shfl_xor(c2, o); }
    const float sil = 1.0f / a, sol = 1.0f / c2;
    if (d == 0) { si[obase + l] = sil; so[obase + l] = sol; }
    qsia += qv * sil;
    ksoa += kvv * sol;
  }
  atomicAdd(&qsi[bh * 64 + d], qsia);
  atomicAdd(&kso[bh * 64 + d], ksoa);
}

// ---------------- r3: sink_allocation + exp(clipped conserved_source) + denom ----------------
__global__ __launch_bounds__(256) void r3_cons(const __bf16* __restrict__ Qp, const __bf16* __restrict__ Kp,
                                               const float* __restrict__ qsi, const float* __restrict__ kso,
                                               float* __restrict__ sa, float* __restrict__ csx,
                                               float* __restrict__ den) {
  const int blk = blockIdx.x;
  const int chunk = blk & 15, bh = blk >> 4;
  const int b = bh >> 4, h = bh & 15;
  const int d = threadIdx.x & 63, w = threadIdx.x >> 6;
  __shared__ float ksoE[64], qsiE[64];
  if (threadIdx.x < 64) ksoE[threadIdx.x] = kso[bh * 64 + threadIdx.x] + EPSc;
  else if (threadIdx.x < 128) qsiE[threadIdx.x - 64] = qsi[bh * 64 + threadIdx.x - 64] + EPSc;
  __syncthreads();
  const float kE = ksoE[d], qE = qsiE[d];
  const size_t base = ((size_t)b * Lc) * Dc + h * 64 + d;
  const size_t obase = (size_t)bh * Lc;
  const int l0 = chunk * 256;
  float eacc = 0.f;
  for (int i = w; i < 256; i += 4) {
    const int l = l0 + i;
    const size_t idx = base + (size_t)l * Dc;
    const float qv = (float)Qp[idx], kvv = (float)Kp[idx];
    float a = (qv + EPSc) * kE;
    float c2 = (kvv + EPSc) * qE;
#pragma unroll
    for (int o = 32; o; o >>= 1) { a += __shfl_xor(a, o); c2 += __shfl_xor(c2, o); }
    if (d == 0) {
      sa[obase + l] = 1.0f / (1.0f + expf(-a));
      const float cl = fminf(1.0f, fmaxf(-1.0f, c2));
      const float e = expf(cl);          // max-free softmax: cl in [-1,1]
      csx[obase + l] = e;
      eacc += e;
    }
  }
  if (d == 0) atomicAdd(&den[bh], eacc);
}

// ---------------- k5: kv[bh][d][m] = sum_l k * (v * scomp) ----------------
__global__ __launch_bounds__(256) void k5_kv(const __bf16* __restrict__ Kp, const __bf16* __restrict__ Vp,
                                             const float* __restrict__ csx, const float* __restrict__ den,
                                             float* __restrict__ kvout) {
  const int bh = blockIdx.x, chunk = blockIdx.y;  // chunk of 512 rows
  const int b = bh >> 4, h = bh & 15;
  const int tid = threadIdx.x;
  const int dq = (tid >> 4) << 2;
  const int mq = (tid & 15) << 2;
  const float sden = 4096.0f / den[bh];
  __shared__ float klds[4][64], vlds[4][64];
  float acc[4][4] = {};
  const int r = tid >> 6, c = tid & 63;
  const size_t rowbase = ((size_t)b * Lc + chunk * 512) * Dc + h * 64;
  const size_t csbase = (size_t)bh * Lc + chunk * 512;
  for (int i = 0; i < 512; i += 4) {
    const size_t idx = rowbase + (size_t)(i + r) * Dc + c;
    const float sc = csx[csbase + i + r] * sden;
    klds[r][c] = (float)Kp[idx];
    vlds[r][c] = (float)Vp[idx] * sc;
    __syncthreads();
#pragma unroll
    for (int rr = 0; rr < 4; ++rr) {
      float kr[4], vr[4];
#pragma unroll
      for (int j = 0; j < 4; ++j) { kr[j] = klds[rr][dq + j]; vr[j] = vlds[rr][mq + j]; }
#pragma unroll
      for (int a = 0; a < 4; ++a)
#pragma unroll
        for (int e = 0; e < 4; ++e) acc[a][e] += kr[a] * vr[e];
    }
    __syncthreads();
  }
#pragma unroll
  for (int a = 0; a < 4; ++a)
#pragma unroll
    for (int e = 0; e < 4; ++e)
      atomicAdd(&kvout[(size_t)bh * 4096 + (dq + a) * 64 + mq + e], acc[a][e]);
}

// ---------------- k6: x = (q*si) @ kv * sa, write bf16 ----------------
__global__ __launch_bounds__(256) void k6_x(const __bf16* __restrict__ Qp,
                                            const float* __restrict__ kvin, const float* __restrict__ si,
                                            const float* __restrict__ sa, __bf16* __restrict__ Xb) {
  const int bh = blockIdx.x, chunk = blockIdx.y;  // chunk of 256 rows
  const int b = bh >> 4, h = bh & 15;
  const int tid = threadIdx.x;
  __shared__ float kvs[4096];
  __shared__ float ql[64][65];
  for (int e = tid; e < 4096; e += 256) kvs[e] = kvin[(size_t)bh * 4096 + e];
  const int rr0 = (tid >> 4) << 2;
  const int mq = (tid & 15) << 2;
  const size_t bL = (size_t)b * Lc;
  const size_t obase = (size_t)bh * Lc;
  for (int g = 0; g < 4; ++g) {
    const int l0 = chunk * 256 + g * 64;
    __syncthreads();
    for (int e = tid; e < 4096; e += 256)
      ql[e >> 6][e & 63] = (float)Qp[(bL + l0 + (e >> 6)) * Dc + h * 64 + (e & 63)];
    __syncthreads();
    float acc[4][4] = {};
#pragma unroll
    for (int d = 0; d < 64; ++d) {
      float kvr[4], qr[4];
#pragma unroll
      for (int j = 0; j < 4; ++j) { qr[j] = ql[rr0 + j][d]; kvr[j] = kvs[d * 64 + mq + j]; }
#pragma unroll
      for (int a = 0; a < 4; ++a)
#pragma unroll
        for (int e = 0; e < 4; ++e) acc[a][e] += qr[a] * kvr[e];
    }
#pragma unroll
    for (int a = 0; a < 4; ++a) {
      const int l = l0 + rr0 + a;
      const float sc = si[obase + l] * sa[obase + l];
      bf16x4 o;
#pragma unroll
      for (int e = 0; e < 4; ++e) o[e] = (__bf16)(acc[a][e] * sc);
      *(bf16x4*)&Xb[(bL + l) * Dc + h * 64 + mq] = o;
    }
  }
}

// ---------------- host ----------------
extern "C" void kernel_launch(void* const* d_in, const int* in_sizes, int n_in,
                              void* d_out, int out_size, void* d_ws, size_t ws_size,
                              hipStream_t stream) {
  const float* Qin = (const float*)d_in[0];
  const float* Kin = (const float*)d_in[1];
  const float* Vin = (const float*)d_in[2];
  const float* Wq = (const float*)d_in[3];
  const float* bq = (const float*)d_in[4];
  const float* Wk = (const float*)d_in[5];
  const float* bk = (const float*)d_in[6];
  const float* Wv = (const float*)d_in[7];
  const float* bv = (const float*)d_in[8];
  const float* Wo = (const float*)d_in[9];
  const float* bo = (const float*)d_in[10];

  const size_t MD = (size_t)Mc * Dc;
  __bf16* Aq = (__bf16*)d_ws;
  __bf16* Ak = Aq + MD;
  __bf16* Av = Ak + MD;
  __bf16* Wqt = Av + MD;
  __bf16* Wkt = Wqt + (size_t)Dc * Dc;
  __bf16* Wvt = Wkt + (size_t)Dc * Dc;
  __bf16* Wot = Wvt + (size_t)Dc * Dc;
  __bf16* Qp = Wot + (size_t)Dc * Dc;
  __bf16* Kp = Qp + MD;
  __bf16* Vp = Kp + MD;
  float* F = (float*)(Vp + MD);
  float* ksum = F;              // 4096
  float* qsum = ksum + 4096;    // 4096
  float* kso = qsum + 4096;     // 4096
  float* qsi = kso + 4096;      // 4096
  float* den = qsi + 4096;      // 64
  float* kv = den + 64;         // 64*4096
  float* si = kv + 262144;
  float* so = si + 262144;
  float* sa = so + 262144;
  float* csx = sa + 262144;
  __bf16* Xb = Aq;              // reuse Aq (dead after Q-GEMM)

  hipMemsetAsync(F, 0, (size_t)(4 * 4096 + 64 + 262144) * sizeof(float), stream);

  const int n4blocks = (int)(MD / 4 / 256);
  conv_bf16<<<n4blocks, 256, 0, stream>>>(Qin, Aq);
  conv_bf16<<<n4blocks, 256, 0, stream>>>(Kin, Ak);
  conv_bf16<<<n4blocks, 256, 0, stream>>>(Vin, Av);
  dim3 wtg(32, 32), wtb(32, 8);
  wt_conv<<<wtg, wtb, 0, stream>>>(Wq, Wqt);
  wt_conv<<<wtg, wtb, 0, stream>>>(Wk, Wkt);
  wt_conv<<<wtg, wtb, 0, stream>>>(Wv, Wvt);
  wt_conv<<<wtg, wtb, 0, stream>>>(Wo, Wot);

  dim3 gg(Mc / 256, Dc / 256);
  gemm256<1, 1, 1><<<gg, 512, 0, stream>>>(Aq, Wqt, bq, Qp, qsum, Mc, Dc, Dc);
  gemm256<1, 1, 1><<<gg, 512, 0, stream>>>(Ak, Wkt, bk, Kp, ksum, Mc, Dc, Dc);
  gemm256<0, 1, 0><<<gg, 512, 0, stream>>>(Av, Wvt, bv, Vp, nullptr, Mc, Dc, Dc);

  r2_flow<<<1024, 256, 0, stream>>>(Qp, Kp, ksum, qsum, si, so, qsi, kso);
  r3_cons<<<1024, 256, 0, stream>>>(Qp, Kp, qsi, kso, sa, csx, den);
  k5_kv<<<dim3(64, 8), 256, 0, stream>>>(Kp, Vp, csx, den, kv);
  k6_x<<<dim3(64, 16), 256, 0, stream>>>(Qp, kv, si, sa, Xb);

  gemm256<0, 0, 0><<<gg, 512, 0, stream>>>(Xb, Wot, bo, d_out, nullptr, Mc, Dc, Dc);
}

// Round 4
// 542.214 us; speedup vs baseline: 1.0344x; 1.0129x over previous
//
#include <hip/hip_runtime.h>

#define Bc 4
#define Lc 4096
#define Dc 1024
#define LDQ 3072
#define Mc (Bc*Lc)
#define EPSc 1e-6f

typedef __bf16 bf16x8 __attribute__((ext_vector_type(8)));
typedef __bf16 bf16x4 __attribute__((ext_vector_type(4)));
typedef float f32x4 __attribute__((ext_vector_type(4)));

typedef __attribute__((address_space(3))) void lds_vt;
typedef const __attribute__((address_space(1))) void gbl_vt;

__device__ __forceinline__ void gll16(const void* g, void* l) {
  __builtin_amdgcn_global_load_lds((gbl_vt*)g, (lds_vt*)l, 16, 0, 0);
}

// ---------------- converts ----------------
__global__ __launch_bounds__(256) void conv_bf16(const float* __restrict__ X, __bf16* __restrict__ Y) {
  const int i = blockIdx.x * 256 + threadIdx.x;
  const float4 v = ((const float4*)X)[i];
  bf16x4 o;
  o[0] = (__bf16)v.x; o[1] = (__bf16)v.y; o[2] = (__bf16)v.z; o[3] = (__bf16)v.w;
  ((bf16x4*)Y)[i] = o;
}

__global__ __launch_bounds__(256) void wt_conv(const float* __restrict__ W, __bf16* __restrict__ Wt) {
  __shared__ float t[32][33];
  const int n0 = blockIdx.x << 5, k0 = blockIdx.y << 5;
  const int tx = threadIdx.x, ty = threadIdx.y;  // block (32,8)
#pragma unroll
  for (int i = 0; i < 4; ++i)
    t[ty + 8 * i][tx] = W[(size_t)(k0 + ty + 8 * i) * Dc + n0 + tx];
  __syncthreads();
#pragma unroll
  for (int i = 0; i < 4; ++i)
    Wt[(size_t)(n0 + ty + 8 * i) * Dc + k0 + tx] = (__bf16)t[tx][ty + 8 * i];
}

// ---------------- GEMM 256x256, BK=64, dbuf, 2-phase (full-tile prefetch, 1 barrier/tile) ----
// FUSED=1: grouped QKV projection. A/W/bias selected per block by col-region; sigmoid on Q,K;
//          col-sum atomics for Q,K; bf16 out at ld=3072.
// FUSED=0: plain C = A@Wt^T + bias, fp32 out at ld=1024.
// MFMA operands SWAPPED (mfma(B,A)) so each lane holds 4 consecutive out-cols -> wide stores.
template <int FUSED>
__global__ __launch_bounds__(512, 2) void gemm256(
    const __bf16* __restrict__ Aq_, const __bf16* __restrict__ Ak_, const __bf16* __restrict__ Av_,
    const __bf16* __restrict__ Wq_, const __bf16* __restrict__ Wk_, const __bf16* __restrict__ Wv_,
    const float* __restrict__ bq_, const float* __restrict__ bk_, const float* __restrict__ bv_,
    void* __restrict__ Cp, float* __restrict__ qsum, float* __restrict__ ksum) {
  __shared__ __bf16 As[2][16384];
  __shared__ __bf16 Bs[2][16384];
  const int tid = threadIdx.x;
  const int lane = tid & 63, w8 = tid >> 6;
  const int wr = w8 >> 2, wc = w8 & 3;          // 2 x 4 waves
  const int lf = lane & 15, kq = lane >> 4;

  // XCD-chunked bijective swizzle; cols fastest within a chunk (A-panel reuse per XCD)
  constexpr int NBY = FUSED ? 12 : 4;
  constexpr int CPX = (64 * NBY) >> 3;
  const int hwlin = blockIdx.x + (blockIdx.y << 6);
  const int swz = (hwlin & 7) * CPX + (hwlin >> 3);
  const int bx = swz / NBY, by = swz - bx * NBY;
  const int row0 = bx << 8, col0 = by << 8;
  const int region = FUSED ? (col0 >> 10) : 0;
  const int colL = FUSED ? (col0 & 1023) : col0;

  const __bf16* Agl = FUSED ? (region == 0 ? Aq_ : (region == 1 ? Ak_ : Av_)) : Aq_;
  const __bf16* Bgl = FUSED ? (region == 0 ? Wq_ : (region == 1 ? Wk_ : Wv_)) : Wq_;
  const float* biasp = FUSED ? (region == 0 ? bq_ : (region == 1 ? bk_ : bv_)) : bq_;
  const __bf16* Ab_g = Agl + (size_t)row0 * 1024;
  const __bf16* Bb_g = Bgl + (size_t)colL * 1024;

  // fragment read bases (element offsets); swizzled 8-elem k-granules
  const int abase = (wr * 128 + lf) * 64;
  const int bbase = (wc * 64 + lf) * 64;
  const int kg0 = (kq ^ (lf & 7)) << 3;
  const int kg1 = ((4 + kq) ^ (lf & 7)) << 3;

#define STG(G, T, U) do { \
    _Pragma("unroll") \
    for (int i_ = 0; i_ < 2; ++i_) { \
      const int j_ = w8 * 128 + i_ * 64 + lane; \
      const int re_ = j_ >> 3, kgd_ = j_ & 7; \
      if ((G) == 0 || (G) == 2) { \
        const int row_ = (re_ & 63) + ((re_ >> 6) << 7) + (((G) == 2) ? 64 : 0); \
        gll16(Ab_g + row_ * 1024 + ((T) << 6) + ((kgd_ ^ (row_ & 7)) << 3), \
              &As[U][row_ * 64 + (kgd_ << 3)]); \
      } else { \
        const int row_ = (re_ & 31) + ((re_ >> 5) << 6) + (((G) == 3) ? 32 : 0); \
        gll16(Bb_g + row_ * 1024 + ((T) << 6) + ((kgd_ ^ (row_ & 7)) << 3), \
              &Bs[U][row_ * 64 + (kgd_ << 3)]); \
      } \
    } \
  } while (0)

#define RDA(AFR, MB) _Pragma("unroll") for (int m_ = 0; m_ < 4; ++m_) { \
    AFR[m_][0] = *(const bf16x8*)(Ab + abase + ((MB) + m_) * 1024 + kg0); \
    AFR[m_][1] = *(const bf16x8*)(Ab + abase + ((MB) + m_) * 1024 + kg1); }
#define RDB(BFR, NB) _Pragma("unroll") for (int n_ = 0; n_ < 2; ++n_) { \
    BFR[n_][0] = *(const bf16x8*)(Bb + bbase + ((NB) + n_) * 1024 + kg0); \
    BFR[n_][1] = *(const bf16x8*)(Bb + bbase + ((NB) + n_) * 1024 + kg1); }
#define MM(MB, NB, AFR, BFR) _Pragma("unroll") for (int m_ = 0; m_ < 4; ++m_) \
    _Pragma("unroll") for (int n_ = 0; n_ < 2; ++n_) \
    _Pragma("unroll") for (int k_ = 0; k_ < 2; ++k_) \
      acc[(MB) + m_][(NB) + n_] = __builtin_amdgcn_mfma_f32_16x16x32_bf16( \
          BFR[n_][k_], AFR[m_][k_], acc[(MB) + m_][(NB) + n_], 0, 0, 0);
#define LGKM0 do { asm volatile("s_waitcnt lgkmcnt(0)" ::: "memory"); \
                   __builtin_amdgcn_sched_barrier(0); } while (0)
#define PRIO1 __builtin_amdgcn_s_setprio(1);
#define PRIO0 __builtin_amdgcn_s_setprio(0);

  f32x4 acc[8][4] = {};

  // prologue: stage tile 0 into buf 0
  STG(0, 0, 0); STG(1, 0, 0); STG(2, 0, 0); STG(3, 0, 0);
  asm volatile("s_waitcnt vmcnt(0)" ::: "memory");
  __builtin_amdgcn_s_barrier();

  for (int t = 0; t < 16; ++t) {
    const int u = t & 1;
    const __bf16* Ab = As[u];
    const __bf16* Bb = Bs[u];
    if (t < 15) { STG(0, t + 1, u ^ 1); STG(1, t + 1, u ^ 1); STG(2, t + 1, u ^ 1); STG(3, t + 1, u ^ 1); }
    bf16x8 af0[4][2], af1[4][2], bf0[2][2], bf1[2][2];
    RDA(af0, 0) RDB(bf0, 0) LGKM0;
    PRIO1 MM(0, 0, af0, bf0) PRIO0
    RDA(af1, 4) LGKM0;
    PRIO1 MM(4, 0, af1, bf0) PRIO0
    RDB(bf1, 2) LGKM0;
    PRIO1 MM(0, 2, af0, bf1) PRIO0
    PRIO1 MM(4, 2, af1, bf1) PRIO0
    asm volatile("s_waitcnt vmcnt(0)" ::: "memory");
    __builtin_amdgcn_s_barrier();
  }
#undef STG
#undef RDA
#undef RDB
#undef MM

  // epilogue (transposed acc): lane -> row = row0+wr*128+lf+mi*16,
  // cols = col0+wc*64+ni*16+kq*4 + (0..3) contiguous -> wide stores.
  const int b_of = row0 >> 12;
  const int orow = row0 + wr * 128 + lf;
  const int ocl = wc * 64 + (kq << 2);
#pragma unroll
  for (int ni = 0; ni < 4; ++ni) {
    const int cl = ocl + (ni << 4);          // 0..255 within tile
    const int cb = colL + cl;                // 0..1023 bias/sum col
    const f32x4 bb = *(const f32x4*)&biasp[cb];
    f32x4 sacc = {0.f, 0.f, 0.f, 0.f};
#pragma unroll
    for (int mi = 0; mi < 8; ++mi) {
      f32x4 v = acc[mi][ni] + bb;
      if (FUSED && region < 2) {
#pragma unroll
        for (int r = 0; r < 4; ++r) v[r] = 1.0f / (1.0f + expf(-v[r]));
      }
      if (FUSED) {
        bf16x4 o;
#pragma unroll
        for (int r = 0; r < 4; ++r) o[r] = (__bf16)v[r];
        *(bf16x4*)&((__bf16*)Cp)[(size_t)(orow + (mi << 4)) * LDQ + col0 + cl] = o;
      } else {
        *(f32x4*)&((float*)Cp)[(size_t)(orow + (mi << 4)) * 1024 + col0 + cl] = v;
      }
      sacc += v;
    }
    if (FUSED && region < 2) {
#pragma unroll
      for (int o = 1; o < 16; o <<= 1) {
        sacc[0] += __shfl_xor(sacc[0], o); sacc[1] += __shfl_xor(sacc[1], o);
        sacc[2] += __shfl_xor(sacc[2], o); sacc[3] += __shfl_xor(sacc[3], o);
      }
      if (lf == 0) {
        float* sums = (region == 0) ? qsum : ksum;
#pragma unroll
        for (int r = 0; r < 4; ++r) atomicAdd(&sums[b_of * 1024 + cb + r], sacc[r]);
      }
    }
  }
}

// ---------------- r2: si/so + accumulate qsi/kso ----------------
__global__ __launch_bounds__(256) void r2_flow(const __bf16* __restrict__ Qp, const __bf16* __restrict__ Kp,
                                               const float* __restrict__ ksum, const float* __restrict__ qsum,
                                               float* __restrict__ si,
                                               float* __restrict__ qsi, float* __restrict__ kso) {
  const int blk = blockIdx.x;
  const int chunk = blk & 15, bh = blk >> 4;
  const int b = bh >> 4, h = bh & 15;
  const int d = threadIdx.x & 63, w = threadIdx.x >> 6;
  __shared__ float ksE[64], qsE[64];
  if (threadIdx.x < 64) ksE[threadIdx.x] = ksum[bh * 64 + threadIdx.x] + EPSc;
  else if (threadIdx.x < 128) qsE[threadIdx.x - 64] = qsum[bh * 64 + threadIdx.x - 64] + EPSc;
  __syncthreads();
  const float kE = ksE[d], qE = qsE[d];
  const size_t base = ((size_t)b * Lc) * LDQ + h * 64 + d;
  const size_t obase = (size_t)bh * Lc;
  float qsia = 0.f, ksoa = 0.f;
  const int l0 = chunk * 256;
  for (int i = w; i < 256; i += 4) {
    const int l = l0 + i;
    const size_t idx = base + (size_t)l * LDQ;
    const float qv = (float)Qp[idx], kvv = (float)Kp[idx];
    float a = (qv + EPSc) * kE;
    float c2 = (kvv + EPSc) * qE;
#pragma unroll
    for (int o = 32; o; o >>= 1) { a += __shfl_xor(a, o); c2 += __shfl_xor(c2, o); }
    const float sil = 1.0f / a, sol = 1.0f / c2;
    if (d == 0) si[obase + l] = sil;
    qsia += qv * sil;
    ksoa += kvv * sol;
  }
  atomicAdd(&qsi[bh * 64 + d], qsia);
  atomicAdd(&kso[bh * 64 + d], ksoa);
}

// ---------------- r3: sink_allocation + exp(clipped conserved_source) + denom ----------------
__global__ __launch_bounds__(256) void r3_cons(const __bf16* __restrict__ Qp, const __bf16* __restrict__ Kp,
                                               const float* __restrict__ qsi, const float* __restrict__ kso,
                                               float* __restrict__ sa, float* __restrict__ csx,
                                               float* __restrict__ den) {
  const int blk = blockIdx.x;
  const int chunk = blk & 15, bh = blk >> 4;
  const int b = bh >> 4, h = bh & 15;
  const int d = threadIdx.x & 63, w = threadIdx.x >> 6;
  __shared__ float ksoE[64], qsiE[64];
  if (threadIdx.x < 64) ksoE[threadIdx.x] = kso[bh * 64 + threadIdx.x] + EPSc;
  else if (threadIdx.x < 128) qsiE[threadIdx.x - 64] = qsi[bh * 64 + threadIdx.x - 64] + EPSc;
  __syncthreads();
  const float kE = ksoE[d], qE = qsiE[d];
  const size_t base = ((size_t)b * Lc) * LDQ + h * 64 + d;
  const size_t obase = (size_t)bh * Lc;
  const int l0 = chunk * 256;
  float eacc = 0.f;
  for (int i = w; i < 256; i += 4) {
    const int l = l0 + i;
    const size_t idx = base + (size_t)l * LDQ;
    const float qv = (float)Qp[idx], kvv = (float)Kp[idx];
    float a = (qv + EPSc) * kE;
    float c2 = (kvv + EPSc) * qE;
#pragma unroll
    for (int o = 32; o; o >>= 1) { a += __shfl_xor(a, o); c2 += __shfl_xor(c2, o); }
    if (d == 0) {
      sa[obase + l] = 1.0f / (1.0f + expf(-a));
      const float cl = fminf(1.0f, fmaxf(-1.0f, c2));
      const float e = expf(cl);          // max-free softmax: cl in [-1,1]
      csx[obase + l] = e;
      eacc += e;
    }
  }
  if (d == 0) atomicAdd(&den[bh], eacc);
}

// ---------------- k5: kv[bh][d][m] = sum_l k * (v * scomp) ----------------
__global__ __launch_bounds__(256) void k5_kv(const __bf16* __restrict__ Kp, const __bf16* __restrict__ Vp,
                                             const float* __restrict__ csx, const float* __restrict__ den,
                                             float* __restrict__ kvout) {
  const int bh = blockIdx.x, chunk = blockIdx.y;  // chunk of 512 rows
  const int b = bh >> 4, h = bh & 15;
  const int tid = threadIdx.x;
  const int dq = (tid >> 4) << 2;
  const int mq = (tid & 15) << 2;
  const float sden = 4096.0f / den[bh];
  __shared__ float klds[4][64], vlds[4][64];
  float acc[4][4] = {};
  const int r = tid >> 6, c = tid & 63;
  const size_t rowbase = ((size_t)b * Lc + chunk * 512) * LDQ + h * 64;
  const size_t csbase = (size_t)bh * Lc + chunk * 512;
  for (int i = 0; i < 512; i += 4) {
    const size_t idx = rowbase + (size_t)(i + r) * LDQ + c;
    const float sc = csx[csbase + i + r] * sden;
    klds[r][c] = (float)Kp[idx];
    vlds[r][c] = (float)Vp[idx] * sc;
    __syncthreads();
#pragma unroll
    for (int rr = 0; rr < 4; ++rr) {
      float kr[4], vr[4];
#pragma unroll
      for (int j = 0; j < 4; ++j) { kr[j] = klds[rr][dq + j]; vr[j] = vlds[rr][mq + j]; }
#pragma unroll
      for (int a = 0; a < 4; ++a)
#pragma unroll
        for (int e = 0; e < 4; ++e) acc[a][e] += kr[a] * vr[e];
    }
    __syncthreads();
  }
#pragma unroll
  for (int a = 0; a < 4; ++a)
#pragma unroll
    for (int e = 0; e < 4; ++e)
      atomicAdd(&kvout[(size_t)bh * 4096 + (dq + a) * 64 + mq + e], acc[a][e]);
}

// ---------------- k6: x = (q*si) @ kv * sa, write bf16 ----------------
__global__ __launch_bounds__(256) void k6_x(const __bf16* __restrict__ Qp,
                                            const float* __restrict__ kvin, const float* __restrict__ si,
                                            const float* __restrict__ sa, __bf16* __restrict__ Xb) {
  const int bh = blockIdx.x, chunk = blockIdx.y;  // chunk of 256 rows
  const int b = bh >> 4, h = bh & 15;
  const int tid = threadIdx.x;
  __shared__ float kvs[4096];
  __shared__ float ql[64][65];
  for (int e = tid; e < 4096; e += 256) kvs[e] = kvin[(size_t)bh * 4096 + e];
  const int rr0 = (tid >> 4) << 2;
  const int mq = (tid & 15) << 2;
  const size_t bL = (size_t)b * Lc;
  const size_t obase = (size_t)bh * Lc;
  for (int g = 0; g < 4; ++g) {
    const int l0 = chunk * 256 + g * 64;
    __syncthreads();
    for (int e = tid; e < 4096; e += 256)
      ql[e >> 6][e & 63] = (float)Qp[(bL + l0 + (e >> 6)) * LDQ + h * 64 + (e & 63)];
    __syncthreads();
    float acc[4][4] = {};
#pragma unroll
    for (int d = 0; d < 64; ++d) {
      float kvr[4], qr[4];
#pragma unroll
      for (int j = 0; j < 4; ++j) { qr[j] = ql[rr0 + j][d]; kvr[j] = kvs[d * 64 + mq + j]; }
#pragma unroll
      for (int a = 0; a < 4; ++a)
#pragma unroll
        for (int e = 0; e < 4; ++e) acc[a][e] += qr[a] * kvr[e];
    }
#pragma unroll
    for (int a = 0; a < 4; ++a) {
      const int l = l0 + rr0 + a;
      const float sc = si[obase + l] * sa[obase + l];
      bf16x4 o;
#pragma unroll
      for (int e = 0; e < 4; ++e) o[e] = (__bf16)(acc[a][e] * sc);
      *(bf16x4*)&Xb[(bL + l) * Dc + h * 64 + mq] = o;
    }
  }
}

// ---------------- host ----------------
extern "C" void kernel_launch(void* const* d_in, const int* in_sizes, int n_in,
                              void* d_out, int out_size, void* d_ws, size_t ws_size,
                              hipStream_t stream) {
  const float* Qin = (const float*)d_in[0];
  const float* Kin = (const float*)d_in[1];
  const float* Vin = (const float*)d_in[2];
  const float* Wq = (const float*)d_in[3];
  const float* bq = (const float*)d_in[4];
  const float* Wk = (const float*)d_in[5];
  const float* bk = (const float*)d_in[6];
  const float* Wv = (const float*)d_in[7];
  const float* bv = (const float*)d_in[8];
  const float* Wo = (const float*)d_in[9];
  const float* bo = (const float*)d_in[10];

  const size_t MD = (size_t)Mc * Dc;
  __bf16* Aq = (__bf16*)d_ws;
  __bf16* Ak = Aq + MD;
  __bf16* Av = Ak + MD;
  __bf16* Wqt = Av + MD;
  __bf16* Wkt = Wqt + (size_t)Dc * Dc;
  __bf16* Wvt = Wkt + (size_t)Dc * Dc;
  __bf16* Wot = Wvt + (size_t)Dc * Dc;
  __bf16* QKV = Wot + (size_t)Dc * Dc;          // [M][3072]
  float* F = (float*)(QKV + (size_t)Mc * LDQ);
  float* ksum = F;              // 4096
  float* qsum = ksum + 4096;    // 4096
  float* kso = qsum + 4096;     // 4096
  float* qsi = kso + 4096;      // 4096
  float* den = qsi + 4096;      // 64
  float* kv = den + 64;         // 64*4096
  float* si = kv + 262144;
  float* sa = si + 262144;
  float* csx = sa + 262144;
  __bf16* Xb = Aq;              // reuse Aq (dead after QKV GEMM)

  hipMemsetAsync(F, 0, (size_t)(4 * 4096 + 64 + 262144) * sizeof(float), stream);

  const int n4blocks = (int)(MD / 4 / 256);
  conv_bf16<<<n4blocks, 256, 0, stream>>>(Qin, Aq);
  conv_bf16<<<n4blocks, 256, 0, stream>>>(Kin, Ak);
  conv_bf16<<<n4blocks, 256, 0, stream>>>(Vin, Av);
  dim3 wtg(32, 32), wtb(32, 8);
  wt_conv<<<wtg, wtb, 0, stream>>>(Wq, Wqt);
  wt_conv<<<wtg, wtb, 0, stream>>>(Wk, Wkt);
  wt_conv<<<wtg, wtb, 0, stream>>>(Wv, Wvt);
  wt_conv<<<wtg, wtb, 0, stream>>>(Wo, Wot);

  // fused grouped QKV projection: one dispatch, 768 blocks
  gemm256<1><<<dim3(64, 12), 512, 0, stream>>>(Aq, Ak, Av, Wqt, Wkt, Wvt,
                                               bq, bk, bv, QKV, qsum, ksum);

  const __bf16* Qp = QKV;
  const __bf16* Kp = QKV + 1024;
  const __bf16* Vp = QKV + 2048;
  r2_flow<<<1024, 256, 0, stream>>>(Qp, Kp, ksum, qsum, si, qsi, kso);
  r3_cons<<<1024, 256, 0, stream>>>(Qp, Kp, qsi, kso, sa, csx, den);
  k5_kv<<<dim3(64, 8), 256, 0, stream>>>(Kp, Vp, csx, den, kv);
  k6_x<<<dim3(64, 16), 256, 0, stream>>>(Qp, kv, si, sa, Xb);

  // output projection: fp32 out
  gemm256<0><<<dim3(64, 4), 512, 0, stream>>>(Xb, nullptr, nullptr, Wot, nullptr, nullptr,
                                              bo, nullptr, nullptr, d_out, nullptr, nullptr);
}

// Round 5
// 522.620 us; speedup vs baseline: 1.0731x; 1.0375x over previous
//
#include <hip/hip_runtime.h>

#define Bc 4
#define Lc 4096
#define Dc 1024
#define LDQ 3072
#define Mc (Bc*Lc)
#define EPSc 1e-6f

typedef __bf16 bf16x8 __attribute__((ext_vector_type(8)));
typedef __bf16 bf16x4 __attribute__((ext_vector_type(4)));
typedef float f32x4 __attribute__((ext_vector_type(4)));

typedef __attribute__((address_space(3))) void lds_vt;
typedef const __attribute__((address_space(1))) void gbl_vt;

__device__ __forceinline__ void gll16(const void* g, void* l) {
  __builtin_amdgcn_global_load_lds((gbl_vt*)g, (lds_vt*)l, 16, 0, 0);
}

// ---------------- converts ----------------
__global__ __launch_bounds__(256) void conv_bf16(const float* __restrict__ X, __bf16* __restrict__ Y) {
  const int i = blockIdx.x * 256 + threadIdx.x;
  const float4 v = ((const float4*)X)[i];
  bf16x4 o;
  o[0] = (__bf16)v.x; o[1] = (__bf16)v.y; o[2] = (__bf16)v.z; o[3] = (__bf16)v.w;
  ((bf16x4*)Y)[i] = o;
}

__global__ __launch_bounds__(256) void wt_conv(const float* __restrict__ W, __bf16* __restrict__ Wt) {
  __shared__ float t[32][33];
  const int n0 = blockIdx.x << 5, k0 = blockIdx.y << 5;
  const int tx = threadIdx.x, ty = threadIdx.y;  // block (32,8)
#pragma unroll
  for (int i = 0; i < 4; ++i)
    t[ty + 8 * i][tx] = W[(size_t)(k0 + ty + 8 * i) * Dc + n0 + tx];
  __syncthreads();
#pragma unroll
  for (int i = 0; i < 4; ++i)
    Wt[(size_t)(n0 + ty + 8 * i) * Dc + k0 + tx] = (__bf16)t[tx][ty + 8 * i];
}

// ---------------- GEMM 256x256, BK=64, dbuf, per-wave-unit staging ----------------
// Schedule: each wave stages ONE 16KB quarter-unit (its 8 gll16) at tile start for
// tile t+1; computes tile t in 4 MFMA quadrants with lgkm-gated ds_reads; then a
// single vmcnt(0) (draining loads issued a full tile ~2500cyc earlier) + 1 barrier.
// FUSED=1: grouped QKV projection (sigmoid Q,K; col-sum atomics; bf16 out ld=3072).
// FUSED=0: plain C = A@Wt^T + bias, fp32 out ld=1024.
// MFMA operands swapped (mfma(B,A)) so each lane holds 4 consecutive out-cols.
template <int FUSED>
__global__ __launch_bounds__(512, 2) void gemm256(
    const __bf16* __restrict__ Aq_, const __bf16* __restrict__ Ak_, const __bf16* __restrict__ Av_,
    const __bf16* __restrict__ Wq_, const __bf16* __restrict__ Wk_, const __bf16* __restrict__ Wv_,
    const float* __restrict__ bq_, const float* __restrict__ bk_, const float* __restrict__ bv_,
    void* __restrict__ Cp, float* __restrict__ qsum, float* __restrict__ ksum) {
  __shared__ __bf16 As[2][16384];
  __shared__ __bf16 Bs[2][16384];
  const int tid = threadIdx.x;
  const int lane = tid & 63, w8 = tid >> 6;
  const int wr = w8 >> 2, wc = w8 & 3;          // 2 x 4 waves
  const int lf = lane & 15, kq = lane >> 4;

  // XCD-chunked bijective swizzle; cols fastest within a chunk (A-panel reuse per XCD)
  constexpr int NBY = FUSED ? 12 : 4;
  constexpr int CPX = (64 * NBY) >> 3;
  const int hwlin = blockIdx.x + (blockIdx.y << 6);
  const int swz = (hwlin & 7) * CPX + (hwlin >> 3);
  const int bx = swz / NBY, by = swz - bx * NBY;
  const int row0 = bx << 8, col0 = by << 8;
  const int region = FUSED ? (col0 >> 10) : 0;
  const int colL = FUSED ? (col0 & 1023) : col0;

  const __bf16* Agl = FUSED ? (region == 0 ? Aq_ : (region == 1 ? Ak_ : Av_)) : Aq_;
  const __bf16* Bgl = FUSED ? (region == 0 ? Wq_ : (region == 1 ? Wk_ : Wv_)) : Wq_;
  const float* biasp = FUSED ? (region == 0 ? bq_ : (region == 1 ? bk_ : bv_)) : bq_;
  const __bf16* Ab_g = Agl + (size_t)row0 * 1024;
  const __bf16* Bb_g = Bgl + (size_t)colL * 1024;

  // fragment read bases (element offsets); swizzled 8-elem k-granules
  const int abase = (wr * 128 + lf) * 64;
  const int bbase = (wc * 64 + lf) * 64;
  const int kg0 = (kq ^ (lf & 7)) << 3;
  const int kg1 = ((4 + kq) ^ (lf & 7)) << 3;

  // Per-wave staging unit: uw = w8>>1 in {A[0:128), A[128:256), B[0:128), B[128:256)};
  // sub = w8&1 selects which half of the unit's 1024 granules this wave loads.
  const int uw = w8 >> 1, sub = w8 & 1;
#define STGW(T, U) do { \
    _Pragma("unroll") \
    for (int i_ = 0; i_ < 8; ++i_) { \
      const int g_ = sub * 512 + i_ * 64 + lane; \
      const int rI_ = g_ >> 3, kgd_ = g_ & 7; \
      const int row_ = ((uw & 1) << 7) + rI_; \
      if (uw < 2) \
        gll16(Ab_g + row_ * 1024 + ((T) << 6) + ((kgd_ ^ (row_ & 7)) << 3), \
              &As[U][row_ * 64 + (kgd_ << 3)]); \
      else \
        gll16(Bb_g + row_ * 1024 + ((T) << 6) + ((kgd_ ^ (row_ & 7)) << 3), \
              &Bs[U][row_ * 64 + (kgd_ << 3)]); \
    } \
    __builtin_amdgcn_sched_barrier(0); \
  } while (0)

#define RDA(AFR, MB) _Pragma("unroll") for (int m_ = 0; m_ < 4; ++m_) { \
    AFR[m_][0] = *(const bf16x8*)(Ab + abase + ((MB) + m_) * 1024 + kg0); \
    AFR[m_][1] = *(const bf16x8*)(Ab + abase + ((MB) + m_) * 1024 + kg1); }
#define RDB(BFR, NB) _Pragma("unroll") for (int n_ = 0; n_ < 2; ++n_) { \
    BFR[n_][0] = *(const bf16x8*)(Bb + bbase + ((NB) + n_) * 1024 + kg0); \
    BFR[n_][1] = *(const bf16x8*)(Bb + bbase + ((NB) + n_) * 1024 + kg1); }
#define MM(MB, NB, AFR, BFR) _Pragma("unroll") for (int m_ = 0; m_ < 4; ++m_) \
    _Pragma("unroll") for (int n_ = 0; n_ < 2; ++n_) \
    _Pragma("unroll") for (int k_ = 0; k_ < 2; ++k_) \
      acc[(MB) + m_][(NB) + n_] = __builtin_amdgcn_mfma_f32_16x16x32_bf16( \
          BFR[n_][k_], AFR[m_][k_], acc[(MB) + m_][(NB) + n_], 0, 0, 0);
#define LGKM0 do { asm volatile("s_waitcnt lgkmcnt(0)" ::: "memory"); \
                   __builtin_amdgcn_sched_barrier(0); } while (0)
#define PRIO1 __builtin_amdgcn_s_setprio(1);
#define PRIO0 __builtin_amdgcn_s_setprio(0);

  f32x4 acc[8][4] = {};

  // prologue: stage tile 0 into buf 0 (each wave its own unit)
  STGW(0, 0);
  asm volatile("s_waitcnt vmcnt(0)" ::: "memory");
  asm volatile("s_barrier" ::: "memory");

  for (int t = 0; t < 16; ++t) {
    const int u = t & 1;
    const __bf16* Ab = As[u];
    const __bf16* Bb = Bs[u];
    if (t < 15) STGW(t + 1, u ^ 1);   // issue early: drained only at tile end
    bf16x8 af0[4][2], af1[4][2], bf0[2][2], bf1[2][2];
    RDA(af0, 0) RDB(bf0, 0) LGKM0;
    PRIO1 MM(0, 0, af0, bf0) PRIO0
    RDA(af1, 4) LGKM0;
    PRIO1 MM(4, 0, af1, bf0) PRIO0
    RDB(bf1, 2) LGKM0;
    PRIO1 MM(0, 2, af0, bf1) PRIO0
    PRIO1 MM(4, 2, af1, bf1) PRIO0
    if (t < 15) asm volatile("s_waitcnt vmcnt(0)" ::: "memory");  // full-tile-old loads
    asm volatile("s_waitcnt lgkmcnt(0)" ::: "memory");
    asm volatile("s_barrier" ::: "memory");
  }
#undef STGW
#undef RDA
#undef RDB
#undef MM

  // epilogue (transposed acc): lane -> row = row0+wr*128+lf+mi*16,
  // cols = col0+wc*64+ni*16+kq*4 + (0..3) contiguous -> wide stores.
  const int b_of = row0 >> 12;
  const int orow = row0 + wr * 128 + lf;
  const int ocl = wc * 64 + (kq << 2);
#pragma unroll
  for (int ni = 0; ni < 4; ++ni) {
    const int cl = ocl + (ni << 4);          // 0..255 within tile
    const int cb = colL + cl;                // 0..1023 bias/sum col
    const f32x4 bb = *(const f32x4*)&biasp[cb];
    f32x4 sacc = {0.f, 0.f, 0.f, 0.f};
#pragma unroll
    for (int mi = 0; mi < 8; ++mi) {
      f32x4 v = acc[mi][ni] + bb;
      if (FUSED && region < 2) {
#pragma unroll
        for (int r = 0; r < 4; ++r) v[r] = 1.0f / (1.0f + expf(-v[r]));
      }
      if (FUSED) {
        bf16x4 o;
#pragma unroll
        for (int r = 0; r < 4; ++r) o[r] = (__bf16)v[r];
        *(bf16x4*)&((__bf16*)Cp)[(size_t)(orow + (mi << 4)) * LDQ + col0 + cl] = o;
      } else {
        *(f32x4*)&((float*)Cp)[(size_t)(orow + (mi << 4)) * 1024 + col0 + cl] = v;
      }
      sacc += v;
    }
    if (FUSED && region < 2) {
#pragma unroll
      for (int o = 1; o < 16; o <<= 1) {
        sacc[0] += __shfl_xor(sacc[0], o); sacc[1] += __shfl_xor(sacc[1], o);
        sacc[2] += __shfl_xor(sacc[2], o); sacc[3] += __shfl_xor(sacc[3], o);
      }
      if (lf == 0) {
        float* sums = (region == 0) ? qsum : ksum;
#pragma unroll
        for (int r = 0; r < 4; ++r) atomicAdd(&sums[b_of * 1024 + cb + r], sacc[r]);
      }
    }
  }
}

// ---------------- r2: si/so + accumulate qsi/kso ----------------
__global__ __launch_bounds__(256) void r2_flow(const __bf16* __restrict__ Qp, const __bf16* __restrict__ Kp,
                                               const float* __restrict__ ksum, const float* __restrict__ qsum,
                                               float* __restrict__ si,
                                               float* __restrict__ qsi, float* __restrict__ kso) {
  const int blk = blockIdx.x;
  const int chunk = blk & 15, bh = blk >> 4;
  const int b = bh >> 4, h = bh & 15;
  const int d = threadIdx.x & 63, w = threadIdx.x >> 6;
  __shared__ float ksE[64], qsE[64];
  if (threadIdx.x < 64) ksE[threadIdx.x] = ksum[bh * 64 + threadIdx.x] + EPSc;
  else if (threadIdx.x < 128) qsE[threadIdx.x - 64] = qsum[bh * 64 + threadIdx.x - 64] + EPSc;
  __syncthreads();
  const float kE = ksE[d], qE = qsE[d];
  const size_t base = ((size_t)b * Lc) * LDQ + h * 64 + d;
  const size_t obase = (size_t)bh * Lc;
  float qsia = 0.f, ksoa = 0.f;
  const int l0 = chunk * 256;
  for (int i = w; i < 256; i += 4) {
    const int l = l0 + i;
    const size_t idx = base + (size_t)l * LDQ;
    const float qv = (float)Qp[idx], kvv = (float)Kp[idx];
    float a = (qv + EPSc) * kE;
    float c2 = (kvv + EPSc) * qE;
#pragma unroll
    for (int o = 32; o; o >>= 1) { a += __shfl_xor(a, o); c2 += __shfl_xor(c2, o); }
    const float sil = 1.0f / a, sol = 1.0f / c2;
    if (d == 0) si[obase + l] = sil;
    qsia += qv * sil;
    ksoa += kvv * sol;
  }
  atomicAdd(&qsi[bh * 64 + d], qsia);
  atomicAdd(&kso[bh * 64 + d], ksoa);
}

// ---------------- r3: sink_allocation + exp(clipped conserved_source) + denom ----------------
__global__ __launch_bounds__(256) void r3_cons(const __bf16* __restrict__ Qp, const __bf16* __restrict__ Kp,
                                               const float* __restrict__ qsi, const float* __restrict__ kso,
                                               float* __restrict__ sa, float* __restrict__ csx,
                                               float* __restrict__ den) {
  const int blk = blockIdx.x;
  const int chunk = blk & 15, bh = blk >> 4;
  const int b = bh >> 4, h = bh & 15;
  const int d = threadIdx.x & 63, w = threadIdx.x >> 6;
  __shared__ float ksoE[64], qsiE[64];
  if (threadIdx.x < 64) ksoE[threadIdx.x] = kso[bh * 64 + threadIdx.x] + EPSc;
  else if (threadIdx.x < 128) qsiE[threadIdx.x - 64] = qsi[bh * 64 + threadIdx.x - 64] + EPSc;
  __syncthreads();
  const float kE = ksoE[d], qE = qsiE[d];
  const size_t base = ((size_t)b * Lc) * LDQ + h * 64 + d;
  const size_t obase = (size_t)bh * Lc;
  const int l0 = chunk * 256;
  float eacc = 0.f;
  for (int i = w; i < 256; i += 4) {
    const int l = l0 + i;
    const size_t idx = base + (size_t)l * LDQ;
    const float qv = (float)Qp[idx], kvv = (float)Kp[idx];
    float a = (qv + EPSc) * kE;
    float c2 = (kvv + EPSc) * qE;
#pragma unroll
    for (int o = 32; o; o >>= 1) { a += __shfl_xor(a, o); c2 += __shfl_xor(c2, o); }
    if (d == 0) {
      sa[obase + l] = 1.0f / (1.0f + expf(-a));
      const float cl = fminf(1.0f, fmaxf(-1.0f, c2));
      const float e = expf(cl);          // max-free softmax: cl in [-1,1]
      csx[obase + l] = e;
      eacc += e;
    }
  }
  if (d == 0) atomicAdd(&den[bh], eacc);
}

// ---------------- k5: kv[bh][d][m] = sum_l k * (v * scomp) ----------------
__global__ __launch_bounds__(256) void k5_kv(const __bf16* __restrict__ Kp, const __bf16* __restrict__ Vp,
                                             const float* __restrict__ csx, const float* __restrict__ den,
                                             float* __restrict__ kvout) {
  const int bh = blockIdx.x, chunk = blockIdx.y;  // chunk of 512 rows
  const int b = bh >> 4, h = bh & 15;
  const int tid = threadIdx.x;
  const int dq = (tid >> 4) << 2;
  const int mq = (tid & 15) << 2;
  const float sden = 4096.0f / den[bh];
  __shared__ float klds[4][64], vlds[4][64];
  float acc[4][4] = {};
  const int r = tid >> 6, c = tid & 63;
  const size_t rowbase = ((size_t)b * Lc + chunk * 512) * LDQ + h * 64;
  const size_t csbase = (size_t)bh * Lc + chunk * 512;
  for (int i = 0; i < 512; i += 4) {
    const size_t idx = rowbase + (size_t)(i + r) * LDQ + c;
    const float sc = csx[csbase + i + r] * sden;
    klds[r][c] = (float)Kp[idx];
    vlds[r][c] = (float)Vp[idx] * sc;
    __syncthreads();
#pragma unroll
    for (int rr = 0; rr < 4; ++rr) {
      float kr[4], vr[4];
#pragma unroll
      for (int j = 0; j < 4; ++j) { kr[j] = klds[rr][dq + j]; vr[j] = vlds[rr][mq + j]; }
#pragma unroll
      for (int a = 0; a < 4; ++a)
#pragma unroll
        for (int e = 0; e < 4; ++e) acc[a][e] += kr[a] * vr[e];
    }
    __syncthreads();
  }
#pragma unroll
  for (int a = 0; a < 4; ++a)
#pragma unroll
    for (int e = 0; e < 4; ++e)
      atomicAdd(&kvout[(size_t)bh * 4096 + (dq + a) * 64 + mq + e], acc[a][e]);
}

// ---------------- k6: x = (q*si) @ kv * sa, write bf16 ----------------
__global__ __launch_bounds__(256) void k6_x(const __bf16* __restrict__ Qp,
                                            const float* __restrict__ kvin, const float* __restrict__ si,
                                            const float* __restrict__ sa, __bf16* __restrict__ Xb) {
  const int bh = blockIdx.x, chunk = blockIdx.y;  // chunk of 256 rows
  const int b = bh >> 4, h = bh & 15;
  const int tid = threadIdx.x;
  __shared__ float kvs[4096];
  __shared__ float ql[64][65];
  for (int e = tid; e < 4096; e += 256) kvs[e] = kvin[(size_t)bh * 4096 + e];
  const int rr0 = (tid >> 4) << 2;
  const int mq = (tid & 15) << 2;
  const size_t bL = (size_t)b * Lc;
  const size_t obase = (size_t)bh * Lc;
  for (int g = 0; g < 4; ++g) {
    const int l0 = chunk * 256 + g * 64;
    __syncthreads();
    for (int e = tid; e < 4096; e += 256)
      ql[e >> 6][e & 63] = (float)Qp[(bL + l0 + (e >> 6)) * LDQ + h * 64 + (e & 63)];
    __syncthreads();
    float acc[4][4] = {};
#pragma unroll
    for (int d = 0; d < 64; ++d) {
      float kvr[4], qr[4];
#pragma unroll
      for (int j = 0; j < 4; ++j) { qr[j] = ql[rr0 + j][d]; kvr[j] = kvs[d * 64 + mq + j]; }
#pragma unroll
      for (int a = 0; a < 4; ++a)
#pragma unroll
        for (int e = 0; e < 4; ++e) acc[a][e] += qr[a] * kvr[e];
    }
#pragma unroll
    for (int a = 0; a < 4; ++a) {
      const int l = l0 + rr0 + a;
      const float sc = si[obase + l] * sa[obase + l];
      bf16x4 o;
#pragma unroll
      for (int e = 0; e < 4; ++e) o[e] = (__bf16)(acc[a][e] * sc);
      *(bf16x4*)&Xb[(bL + l) * Dc + h * 64 + mq] = o;
    }
  }
}

// ---------------- host ----------------
extern "C" void kernel_launch(void* const* d_in, const int* in_sizes, int n_in,
                              void* d_out, int out_size, void* d_ws, size_t ws_size,
                              hipStream_t stream) {
  const float* Qin = (const float*)d_in[0];
  const float* Kin = (const float*)d_in[1];
  const float* Vin = (const float*)d_in[2];
  const float* Wq = (const float*)d_in[3];
  const float* bq = (const float*)d_in[4];
  const float* Wk = (const float*)d_in[5];
  const float* bk = (const float*)d_in[6];
  const float* Wv = (const float*)d_in[7];
  const float* bv = (const float*)d_in[8];
  const float* Wo = (const float*)d_in[9];
  const float* bo = (const float*)d_in[10];

  const size_t MD = (size_t)Mc * Dc;
  __bf16* Aq = (__bf16*)d_ws;
  __bf16* Ak = Aq + MD;
  __bf16* Av = Ak + MD;
  __bf16* Wqt = Av + MD;
  __bf16* Wkt = Wqt + (size_t)Dc * Dc;
  __bf16* Wvt = Wkt + (size_t)Dc * Dc;
  __bf16* Wot = Wvt + (size_t)Dc * Dc;
  __bf16* QKV = Wot + (size_t)Dc * Dc;          // [M][3072]
  float* F = (float*)(QKV + (size_t)Mc * LDQ);
  float* ksum = F;              // 4096
  float* qsum = ksum + 4096;    // 4096
  float* kso = qsum + 4096;     // 4096
  float* qsi = kso + 4096;      // 4096
  float* den = qsi + 4096;      // 64
  float* kv = den + 64;         // 64*4096
  float* si = kv + 262144;
  float* sa = si + 262144;
  float* csx = sa + 262144;
  __bf16* Xb = Aq;              // reuse Aq (dead after QKV GEMM)

  hipMemsetAsync(F, 0, (size_t)(4 * 4096 + 64 + 262144) * sizeof(float), stream);

  const int n4blocks = (int)(MD / 4 / 256);
  conv_bf16<<<n4blocks, 256, 0, stream>>>(Qin, Aq);
  conv_bf16<<<n4blocks, 256, 0, stream>>>(Kin, Ak);
  conv_bf16<<<n4blocks, 256, 0, stream>>>(Vin, Av);
  dim3 wtg(32, 32), wtb(32, 8);
  wt_conv<<<wtg, wtb, 0, stream>>>(Wq, Wqt);
  wt_conv<<<wtg, wtb, 0, stream>>>(Wk, Wkt);
  wt_conv<<<wtg, wtb, 0, stream>>>(Wv, Wvt);
  wt_conv<<<wtg, wtb, 0, stream>>>(Wo, Wot);

  // fused grouped QKV projection: one dispatch, 768 blocks
  gemm256<1><<<dim3(64, 12), 512, 0, stream>>>(Aq, Ak, Av, Wqt, Wkt, Wvt,
                                               bq, bk, bv, QKV, qsum, ksum);

  const __bf16* Qp = QKV;
  const __bf16* Kp = QKV + 1024;
  const __bf16* Vp = QKV + 2048;
  r2_flow<<<1024, 256, 0, stream>>>(Qp, Kp, ksum, qsum, si, qsi, kso);
  r3_cons<<<1024, 256, 0, stream>>>(Qp, Kp, qsi, kso, sa, csx, den);
  k5_kv<<<dim3(64, 8), 256, 0, stream>>>(Kp, Vp, csx, den, kv);
  k6_x<<<dim3(64, 16), 256, 0, stream>>>(Qp, kv, si, sa, Xb);

  // output projection: fp32 out
  gemm256<0><<<dim3(64, 4), 512, 0, stream>>>(Xb, nullptr, nullptr, Wot, nullptr, nullptr,
                                              bo, nullptr, nullptr, d_out, nullptr, nullptr);
}